// Round 11
// baseline (280.868 us; speedup 1.0000x reference)
//
#include <hip/hip_runtime.h>
#include <math.h>

#define B_ 4
#define N_ 250000
#define K_ 32
#define NB 4096    // fine buckets: (bits(qc) >> 19); nonneg floats -> <= 4080
#define NB2 2048   // coarse neg-table buckets: (bits >> 20)
#define KG 4       // segs grouped per hist block
#define HCH 16     // hist chunks over N  (N_/16 = 15625 exact)
#define PKG 4      // segs grouped per pass2neg block
#define PCH 40     // pass2 chunks over N (N_/40 = 6250 exact)
               // R10 post-mortem: PCH=20 gave only 10 waves/CU -> latency-bound
               // (occupancy 19%). PCH=40 -> 5120 waves = 20/CU, keeps PKG=4 sharing.
#define SC 4       // segstats chunks per seg
#define SLOT_SHIFT 13  // 8192 entries per seg in list

// ws layout: small accums @0 (8KB), p05 @8192, emb4 @65536 (16MB),
// hneg_g @+16MB (2MB), tabN (2MB, zeroed with hneg), list (4MB u32)

__device__ __forceinline__ float quad_qc(float4 e, float sex, float sey, float sez,
                                         float tx, float ty, float tz, float A) {
  // explicit fmaf chain => bit-identical across kernels (bucket match requirement)
  float q = fmaf(e.x, fmaf(sex, e.x, -tx),
            fmaf(e.y, fmaf(sey, e.y, -ty),
            fmaf(e.z, fmaf(sez, e.z, -tz), A)));
  return fmaxf(q, 0.f);
}

__device__ __forceinline__ float fast_rcp(float x) { return __builtin_amdgcn_rcpf(x); }
__device__ __forceinline__ float fast_tanh(float x) {
  return 1.f - 2.f * fast_rcp(__expf(2.f * x) + 1.f);
}
__device__ __forceinline__ float fast_sigmoid(float x) {
  return fast_rcp(1.f + __expf(-x));
}

// emb compute + positive-list compaction (block reservation)
__global__ __launch_bounds__(256) void k_emb(
    const float* __restrict__ off, const float* __restrict__ crd,
    const float* __restrict__ seed, const int* __restrict__ inst,
    float* __restrict__ seed_bg, float4* __restrict__ emb4,
    uint32_t* __restrict__ cursor, uint32_t* __restrict__ list)
{
  __shared__ uint32_t lcnt[K_], lbase[K_];
  __shared__ float red[4];
  const int b = blockIdx.y;
  const int tid = threadIdx.x;
  if (tid < K_) lcnt[tid] = 0;
  __syncthreads();

  const int n0 = blockIdx.x * 1024 + tid * 4;   // N_ % 4 == 0
  int kv[4];
  const bool valid = (n0 < N_);
  float sbg = 0.f;

  if (valid) {
    const int idx = b * N_ + n0;
    const float4* o4 = (const float4*)&off[(size_t)idx * 3];
    const float4* c4 = (const float4*)&crd[(size_t)idx * 3];
    float4 o0 = o4[0], o1 = o4[1], o2 = o4[2];
    float4 c0 = c4[0], c1 = c4[1], c2 = c4[2];
    int4 ki = *(const int4*)&inst[idx];
    kv[0] = ki.x; kv[1] = ki.y; kv[2] = ki.z; kv[3] = ki.w;

    emb4[idx + 0] = make_float4(fast_tanh(o0.x) + c0.x, fast_tanh(o0.y) + c0.y,
                                fast_tanh(o0.z) + c0.z, 0.f);
    emb4[idx + 1] = make_float4(fast_tanh(o0.w) + c0.w, fast_tanh(o1.x) + c1.x,
                                fast_tanh(o1.y) + c1.y, 0.f);
    emb4[idx + 2] = make_float4(fast_tanh(o1.z) + c1.z, fast_tanh(o1.w) + c1.w,
                                fast_tanh(o2.x) + c2.x, 0.f);
    emb4[idx + 3] = make_float4(fast_tanh(o2.y) + c2.y, fast_tanh(o2.z) + c2.z,
                                fast_tanh(o2.w) + c2.w, 0.f);

#pragma unroll
    for (int j = 0; j < 4; ++j) {
      if (kv[j] >= 0) {
        atomicAdd(&lcnt[kv[j]], 1u);
      } else {
        float s = fast_sigmoid(seed[idx + j]);
        sbg = fmaf(s, s, sbg);
      }
    }
  }
  __syncthreads();
  if (tid < K_) {
    uint32_t c = lcnt[tid];
    lbase[tid] = c ? atomicAdd(&cursor[b * K_ + tid], c) : 0u;
    lcnt[tid] = 0;
  }
  __syncthreads();
  if (valid) {
#pragma unroll
    for (int j = 0; j < 4; ++j) {
      if (kv[j] >= 0) {
        uint32_t r = atomicAdd(&lcnt[kv[j]], 1u);
        list[(uint32_t)((b * K_ + kv[j]) << SLOT_SHIFT) + lbase[kv[j]] + r] =
            (uint32_t)(n0 + j);
      }
    }
  }
  for (int d = 32; d > 0; d >>= 1) sbg += __shfl_down(sbg, d, 64);
  int wid = tid >> 6, lane = tid & 63;
  if (lane == 0) red[wid] = sbg;
  __syncthreads();
  if (tid == 0) atomicAdd(&seed_bg[b], red[0] + red[1] + red[2] + red[3]);
}

// per-seg stats as a clean reduction over the compacted list (no contention)
__global__ __launch_bounds__(256) void k_segstats(
    const float4* __restrict__ emb4, const float* __restrict__ sig,
    const uint32_t* __restrict__ list, const uint32_t* __restrict__ cursor,
    float* __restrict__ acc)
{
  __shared__ float red[4 * 8];
  const int seg = blockIdx.x >> 2;        // / SC
  const int c = blockIdx.x & (SC - 1);
  const int b = seg >> 5;
  const int G = (int)cursor[seg];
  if (G == 0) return;
  const int i0 = (int)((long)G * c / SC);
  const int i1 = (int)((long)G * (c + 1) / SC);
  const int base = b * N_;
  const uint32_t lo = (uint32_t)(seg << SLOT_SHIFT);
  const int tid = threadIdx.x;

  float sex_ = 0.f, sey_ = 0.f, sez_ = 0.f;
  float ssx = 0.f, ssy = 0.f, ssz = 0.f, ss2 = 0.f;
  for (int i = i0 + tid; i < i1; i += 256) {
    int idx = base + (int)list[lo + i];
    float4 e = emb4[idx];
    float sx = sig[(size_t)idx * 3 + 0];
    float sy = sig[(size_t)idx * 3 + 1];
    float sz = sig[(size_t)idx * 3 + 2];
    sex_ += e.x; sey_ += e.y; sez_ += e.z;
    ssx += sx; ssy += sy; ssz += sz;
    ss2 = fmaf(sx, sx, fmaf(sy, sy, fmaf(sz, sz, ss2)));
  }
  for (int d = 32; d > 0; d >>= 1) {
    sex_ += __shfl_down(sex_, d, 64); sey_ += __shfl_down(sey_, d, 64);
    sez_ += __shfl_down(sez_, d, 64); ssx  += __shfl_down(ssx,  d, 64);
    ssy  += __shfl_down(ssy,  d, 64); ssz  += __shfl_down(ssz,  d, 64);
    ss2  += __shfl_down(ss2,  d, 64);
  }
  int wid = tid >> 6, lane = tid & 63;
  if (lane == 0) {
    float* r = &red[wid * 8];
    r[0] = sex_; r[1] = sey_; r[2] = sez_;
    r[3] = ssx;  r[4] = ssy;  r[5] = ssz; r[6] = ss2;
  }
  __syncthreads();
  if (tid == 0) {
    float v[7];
    for (int f = 0; f < 7; ++f)
      v[f] = red[f] + red[8 + f] + red[16 + f] + red[24 + f];
    float* a = &acc[seg * 8];
    atomicAdd(&a[0], (float)(i1 - i0));
    atomicAdd(&a[1], v[0]); atomicAdd(&a[2], v[1]); atomicAdd(&a[3], v[2]);
    atomicAdd(&a[4], v[3]); atomicAdd(&a[5], v[4]); atomicAdd(&a[6], v[5]);
    atomicAdd(&a[7], v[6]);
  }
}

__global__ void k_params(const float* __restrict__ acc, float* __restrict__ p05)
{
  int seg = threadIdx.x;  // 0..127
  const float* a = &acc[seg * 8];
  float counts = a[0];
  float cnt = fmaxf(counts, 1.f);
  float inv = 1.f / cnt;
  float cx = a[1] * inv, cy = a[2] * inv, cz = a[3] * inv;
  float skx = a[4] * inv, sky = a[5] * inv, skz = a[6] * inv;
  float sex = expf(10.f * skx), sey = expf(10.f * sky), sez = expf(10.f * skz);
  float dev2 = a[7] - 2.f * (a[4] * skx + a[5] * sky + a[6] * skz)
             + counts * (skx * skx + sky * sky + skz * skz);
  float smooth = dev2 / (cnt * 3.f);
  float A = sex * cx * cx + sey * cy * cy + sez * cz * cz;
  float* o = &p05[seg * 16];
  o[0] = sex; o[1] = sey; o[2] = sez;
  o[3] = 2.f * sex * cx; o[4] = 2.f * sey * cy; o[5] = 2.f * sez * cz;
  o[6] = A; o[7] = counts; o[8] = (counts > 0.f) ? 1.f : 0.f; o[9] = smooth;
}

// grouped histogram: KG segs share each emb4 load; 4 x 16KB LDS hists (u32 only)
__global__ __launch_bounds__(512) void k_hist(
    const float4* __restrict__ emb4, const float* __restrict__ p05,
    uint32_t* __restrict__ hneg_g)
{
  __shared__ uint32_t h[KG * NB];   // 64 KB
  const int c = blockIdx.x & (HCH - 1);
  const int kg = blockIdx.x >> 4;
  const int b = blockIdx.y;
  const int seg0 = b * K_ + kg * KG;
  const int tid = threadIdx.x;

  float sexA[KG], seyA[KG], sezA[KG], txA[KG], tyA[KG], tzA[KG], AA[KG];
#pragma unroll
  for (int j = 0; j < KG; ++j) {
    const float* pp = &p05[(seg0 + j) * 16];
    sexA[j] = pp[0]; seyA[j] = pp[1]; sezA[j] = pp[2];
    txA[j] = pp[3]; tyA[j] = pp[4]; tzA[j] = pp[5]; AA[j] = pp[6];
  }
  for (int i = tid; i < KG * NB; i += 512) h[i] = 0;
  __syncthreads();

  const int base = b * N_;
  const int n0 = c * (N_ / HCH);
  const int n1 = n0 + (N_ / HCH);
  for (int n = n0 + tid; n < n1; n += 512) {
    float4 e = emb4[base + n];
#pragma unroll
    for (int j = 0; j < KG; ++j) {
      float qc = quad_qc(e, sexA[j], seyA[j], sezA[j], txA[j], tyA[j], tzA[j], AA[j]);
      atomicAdd(&h[j * NB + (__float_as_uint(qc) >> 19)], 1u);
    }
  }
  __syncthreads();
#pragma unroll
  for (int j = 0; j < KG; ++j) {
    uint32_t* gn = &hneg_g[(seg0 + j) * NB];
    for (int i = tid; i < NB; i += 512) {
      uint32_t v = h[j * NB + i];
      if (v) atomicAdd(&gn[i], v);
    }
  }
}

__device__ __forceinline__ void scan_excl(uint32_t* h, uint32_t* wsum, int tid)
{
  const int chunk = NB >> 10;  // 4
  const int base = tid * chunk;
  uint32_t vals[4];
  uint32_t s = 0;
  for (int i = 0; i < chunk; ++i) { vals[i] = h[base + i]; s += vals[i]; }
  uint32_t x = s;
  int lane = tid & 63;
  for (int d = 1; d < 64; d <<= 1) {
    uint32_t y = (uint32_t)__shfl_up((int)x, d, 64);
    if (lane >= d) x += y;
  }
  int wid = tid >> 6;
  if (lane == 63) wsum[wid] = x;
  __syncthreads();
  if (tid == 0) {
    uint32_t a = 0;
    for (int w = 0; w < 16; ++w) { uint32_t t = wsum[w]; wsum[w] = a; a += t; }
  }
  __syncthreads();
  uint32_t run = wsum[wid] + (x - s);
  for (int i = 0; i < chunk; ++i) { uint32_t t = vals[i]; h[base + i] = run; run += t; }
  __syncthreads();
}

// per-seg: remove positives from neg hist, build pos hist, scan both,
// emit COARSE fused neg table {u,v} (NB2), compute positive contributions
// (incl. subtracting the spurious coarse neg-style term pass2neg will add).
__global__ __launch_bounds__(1024) void k_scanpos(
    const float4* __restrict__ emb4, const float* __restrict__ seed,
    const float* __restrict__ p05, const uint32_t* __restrict__ list,
    uint32_t* __restrict__ hneg_g, float2* __restrict__ tabN,
    float* __restrict__ lov_out, float* __restrict__ seed_fg)
{
  __shared__ uint32_t hn[NB];
  __shared__ uint32_t hp[NB];
  __shared__ uint32_t wsum[16];
  __shared__ float red[32];
  const int seg = blockIdx.x;
  const int b = seg >> 5;
  const float* pp = &p05[seg * 16];
  const float Gf = pp[7];
  if (Gf <= 0.f) return;     // tabN stays zeroed -> pass2neg adds exact 0
  const float sex = pp[0], sey = pp[1], sez = pp[2];
  const float tx = pp[3], ty = pp[4], tz = pp[5], A = pp[6];
  const int tid = threadIdx.x;
  const int base = b * N_;
  const int G = (int)Gf;
  const uint32_t lo = (uint32_t)(seg << SLOT_SHIFT);
  const float Nnegf = (float)N_ - Gf;

  uint32_t* gn = &hneg_g[seg * NB];
  for (int i = tid; i < NB; i += 1024) { hn[i] = gn[i]; hp[i] = 0; }
  __syncthreads();

  // fixup: move this seg's positives out of hn, into hp (exp/log on 3% only)
  for (int i = tid; i < G; i += 1024) {
    int n = (int)list[lo + i];
    float qc = quad_qc(emb4[base + n], sex, sey, sez, tx, ty, tz, A);
    atomicAdd(&hn[__float_as_uint(qc) >> 19], 0xFFFFFFFFu);  // -1
    float p = __expf(-qc);
    float qs = -__logf(1.f - p);   // p==1 -> +inf -> bucket 4080, fine
    atomicAdd(&hp[__float_as_uint(qs) >> 19], 1u);
  }
  __syncthreads();
  scan_excl(hn, wsum, tid);
  scan_excl(hp, wsum, tid);

  // coarse fused neg table (sampled from fine cumulative scans at even idx)
  float2* tN = &tabN[(size_t)seg * NB2];
  for (int bkt = tid; bkt < NB2; bkt += 1024) {
    float R  = (float)hn[2 * bkt];
    float nn = (bkt < NB2 - 1) ? (float)hn[2 * bkt + 2] : Nnegf;
    float m  = nn - R;
    float pb = (float)hp[2 * bkt];
    float pn = (bkt < NB2 - 1) ? (float)hp[2 * bkt + 2] : Gf;
    float gr = Gf + R;
    float psi2 = 2.f / (gr * (gr + m));
    float u = psi2 * (Gf - pb);
    float v = psi2 * (pn - pb) * (1.f / 1048576.f);
    tN[bkt] = make_float2(u, v);
  }

  // positives' own contributions (fine-grained F interp)
  float lov = 0.f, sfg = 0.f;
  for (int i = tid; i < G; i += 1024) {
    int n = (int)list[lo + i];
    float qc = quad_qc(emb4[base + n], sex, sey, sez, tx, ty, tz, A);
    float p = __expf(-qc);
    float qs = -__logf(1.f - p);
    uint32_t qb = __float_as_uint(qs);
    uint32_t bk = qb >> 19;
    float frac = (float)(qb & 0x7FFFFu) * (1.f / 524288.f);
    float R  = (float)hn[bk];
    float nn = (bk < NB - 1) ? (float)hn[bk + 1] : Nnegf;
    float F = R + frac * (nn - R);
    lov += (2.f - 2.f * p) / (Gf + F);
    float s = fast_sigmoid(seed[base + n]);
    float d = s - p;
    sfg += d * d;
    // subtract the spurious COARSE neg-style term (bit-identical to table path)
    uint32_t cb = __float_as_uint(qc);
    uint32_t b2 = cb >> 20;
    float fr = (float)(cb & 0xFFFFFu);
    float R2  = (float)hn[2 * b2];
    float nn2 = (b2 < NB2 - 1) ? (float)hn[2 * b2 + 2] : Nnegf;
    float m2  = nn2 - R2;
    float pb2 = (float)hp[2 * b2];
    float pn2 = (b2 < NB2 - 1) ? (float)hp[2 * b2 + 2] : Gf;
    float gr2 = Gf + R2;
    float psi2 = 2.f / (gr2 * (gr2 + m2));
    float u2 = psi2 * (Gf - pb2);
    float v2 = psi2 * (pn2 - pb2) * (1.f / 1048576.f);
    lov -= p * fmaf(-v2, fr, u2);
  }

  for (int d = 32; d > 0; d >>= 1) {
    lov += __shfl_down(lov, d, 64);
    sfg += __shfl_down(sfg, d, 64);
  }
  int wid = tid >> 6, lane = tid & 63;
  if (lane == 0) { red[wid] = lov; red[16 + wid] = sfg; }
  __syncthreads();
  if (tid == 0) {
    float lt = 0.f, st = 0.f;
    for (int w = 0; w < 16; ++w) { lt += red[w]; st += red[16 + w]; }
    atomicAdd(&lov_out[seg], lt);
    atomicAdd(&seed_fg[b], st);
  }
}

// grouped branch-free negative pass: PKG segs share each emb4 load; grid
// sized for 20 waves/CU (R10 post-mortem: 10 waves/CU was latency-bound).
// Tables stay GLOBAL (hot region ~4 cache lines/seg -> L1 serves gathers);
// invalid segs have zeroed tables -> contribution exactly 0.
__global__ __launch_bounds__(256) void k_pass2neg(
    const float4* __restrict__ emb4, const float* __restrict__ p05,
    const float2* __restrict__ tabN, float* __restrict__ lov_out)
{
  const int c = blockIdx.x % PCH;
  const int kg = blockIdx.x / PCH;
  const int b = blockIdx.y;
  const int seg0 = b * K_ + kg * PKG;
  const int tid = threadIdx.x;

  float sexA[PKG], seyA[PKG], sezA[PKG], txA[PKG], tyA[PKG], tzA[PKG], AA[PKG];
#pragma unroll
  for (int j = 0; j < PKG; ++j) {
    const float* pp = &p05[(seg0 + j) * 16];
    sexA[j] = pp[0]; seyA[j] = pp[1]; sezA[j] = pp[2];
    txA[j] = pp[3]; tyA[j] = pp[4]; tzA[j] = pp[5]; AA[j] = pp[6];
  }
  const float2* tN0 = &tabN[(size_t)(seg0 + 0) * NB2];
  const float2* tN1 = &tabN[(size_t)(seg0 + 1) * NB2];
  const float2* tN2 = &tabN[(size_t)(seg0 + 2) * NB2];
  const float2* tN3 = &tabN[(size_t)(seg0 + 3) * NB2];

  const int base = b * N_;
  const int n0 = c * (N_ / PCH);
  const int n1 = n0 + (N_ / PCH);
  float l0 = 0.f, l1 = 0.f, l2 = 0.f, l3 = 0.f;
  for (int n = n0 + tid; n < n1; n += 256) {
    float4 e = emb4[base + n];
    float q0 = quad_qc(e, sexA[0], seyA[0], sezA[0], txA[0], tyA[0], tzA[0], AA[0]);
    float q1 = quad_qc(e, sexA[1], seyA[1], sezA[1], txA[1], tyA[1], tzA[1], AA[1]);
    float q2 = quad_qc(e, sexA[2], seyA[2], sezA[2], txA[2], tyA[2], tzA[2], AA[2]);
    float q3 = quad_qc(e, sexA[3], seyA[3], sezA[3], txA[3], tyA[3], tzA[3], AA[3]);
    uint32_t c0 = __float_as_uint(q0), c1 = __float_as_uint(q1);
    uint32_t c2 = __float_as_uint(q2), c3 = __float_as_uint(q3);
    float2 t0 = tN0[c0 >> 20];
    float2 t1 = tN1[c1 >> 20];
    float2 t2 = tN2[c2 >> 20];
    float2 t3 = tN3[c3 >> 20];
    float p0 = __expf(-q0), p1 = __expf(-q1);
    float p2 = __expf(-q2), p3 = __expf(-q3);
    l0 = fmaf(p0, fmaf(-t0.y, (float)(c0 & 0xFFFFFu), t0.x), l0);
    l1 = fmaf(p1, fmaf(-t1.y, (float)(c1 & 0xFFFFFu), t1.x), l1);
    l2 = fmaf(p2, fmaf(-t2.y, (float)(c2 & 0xFFFFFu), t2.x), l2);
    l3 = fmaf(p3, fmaf(-t3.y, (float)(c3 & 0xFFFFFu), t3.x), l3);
  }

  float accs[PKG] = {l0, l1, l2, l3};
  int lane = tid & 63;
#pragma unroll
  for (int j = 0; j < PKG; ++j) {
    float v = accs[j];
    for (int d = 32; d > 0; d >>= 1) v += __shfl_down(v, d, 64);
    if (lane == 0) atomicAdd(&lov_out[seg0 + j], v);
  }
}

__global__ void k_final(const float* __restrict__ p05, const float* __restrict__ lov,
                        const float* __restrict__ seed_bg, const float* __restrict__ seed_fg,
                        float* __restrict__ out)
{
  __shared__ float sv[B_], sl[B_], ss[B_];
  int tid = threadIdx.x;   // 128 threads, one per seg
  if (tid < B_) { sv[tid] = 0.f; sl[tid] = 0.f; ss[tid] = 0.f; }
  __syncthreads();
  int b = tid >> 5;
  float vf = p05[tid * 16 + 8];
  atomicAdd(&sv[b], vf);
  atomicAdd(&sl[b], lov[tid] * vf);
  atomicAdd(&ss[b], p05[tid * 16 + 9] * vf);
  __syncthreads();
  if (tid == 0) {
    float total = 0.f;
    for (int bb = 0; bb < B_; ++bb) {
      float obj = fmaxf(sv[bb], 1.f);
      float seed_l = (seed_bg[bb] + seed_fg[bb]) / (float)N_;
      total += sl[bb] / obj + 10.f * (ss[bb] / obj) + 10.f * seed_l;
    }
    out[0] = total / (float)B_;
  }
}

extern "C" void kernel_launch(void* const* d_in, const int* in_sizes, int n_in,
                              void* d_out, int out_size, void* d_ws, size_t ws_size,
                              hipStream_t stream) {
  const float* off  = (const float*)d_in[0];
  const float* crd  = (const float*)d_in[1];
  const float* sig  = (const float*)d_in[2];
  const float* seed = (const float*)d_in[3];
  const int*   inst = (const int*)d_in[4];

  float* ws      = (float*)d_ws;
  float* acc     = ws;                 // 1024 floats
  float* seed_bg = ws + 1024;          // 4
  float* seed_fg = ws + 1028;          // 4
  float* lov     = ws + 1032;          // 128
  uint32_t* cursor = (uint32_t*)(ws + 1160);  // 128
  float* p05     = ws + 2048;          // byte 8192
  char* pbase = (char*)d_ws;
  float4*   emb4   = (float4*)(pbase + 65536);                      // 16 MB
  uint32_t* hneg_g = (uint32_t*)(pbase + 65536 + 16000000);         // 2 MB
  float2*   tabN   = (float2*)(pbase + 65536 + 16000000 + 2097152); // 2 MB coarse
  uint32_t* list   = (uint32_t*)((char*)tabN + 2097152);            // 4 MB

  hipMemsetAsync(d_ws, 0, 8192, stream);
  hipMemsetAsync(hneg_g, 0, 4194304, stream);   // hneg_g + tabN (adjacent)

  dim3 ge((N_ + 1023) / 1024, B_);   // 245 x 4
  k_emb<<<ge, 256, 0, stream>>>(off, crd, seed, inst, seed_bg, emb4, cursor, list);
  k_segstats<<<B_ * K_ * SC, 256, 0, stream>>>(emb4, sig, list, cursor, acc);
  k_params<<<1, 128, 0, stream>>>(acc, p05);
  dim3 gh((K_ / KG) * HCH, B_);      // (8*16) x 4 = 512 blocks
  k_hist<<<gh, 512, 0, stream>>>(emb4, p05, hneg_g);
  k_scanpos<<<B_ * K_, 1024, 0, stream>>>(emb4, seed, p05, list, hneg_g, tabN, lov, seed_fg);
  dim3 gp((K_ / PKG) * PCH, B_);     // (8*40) x 4 = 1280 blocks
  k_pass2neg<<<gp, 256, 0, stream>>>(emb4, p05, tabN, lov);
  k_final<<<1, 128, 0, stream>>>(p05, lov, seed_bg, seed_fg, (float*)d_out);
}

// Round 12
// 214.761 us; speedup vs baseline: 1.3078x; 1.3078x over previous
//
#include <hip/hip_runtime.h>
#include <math.h>

#define B_ 4
#define N_ 250000
#define K_ 32
#define NB 4096    // fine buckets: (bits(qc) >> 19); nonneg floats -> <= 4080
#define NB2 2048   // coarse neg-table buckets: (bits >> 20)
#define KG 4       // segs grouped per hist block
#define HCH 16     // hist chunks over N  (N_/16 = 15625 exact)
#define S2 16      // pass2 chunks over N (R8 shape: best measured, 42.6 us;
                   // LDS-table (R7), PKG grouping (R10/R11) all regressed)
#define SC 4       // segstats chunks per seg
#define SLOT_SHIFT 13  // 8192 entries per seg in list

// ws layout: small accums @0 (8KB), p05 @8192, emb4 @65536 (16MB),
// hneg_g @+16MB (2MB), tabN (2MB, zeroed with hneg), list (4MB u32)

__device__ __forceinline__ float quad_qc(float4 e, float sex, float sey, float sez,
                                         float tx, float ty, float tz, float A) {
  // explicit fmaf chain => bit-identical across kernels (bucket match requirement)
  float q = fmaf(e.x, fmaf(sex, e.x, -tx),
            fmaf(e.y, fmaf(sey, e.y, -ty),
            fmaf(e.z, fmaf(sez, e.z, -tz), A)));
  return fmaxf(q, 0.f);
}

__device__ __forceinline__ float fast_rcp(float x) { return __builtin_amdgcn_rcpf(x); }
__device__ __forceinline__ float fast_tanh(float x) {
  return 1.f - 2.f * fast_rcp(__expf(2.f * x) + 1.f);
}
__device__ __forceinline__ float fast_sigmoid(float x) {
  return fast_rcp(1.f + __expf(-x));
}

// emb compute + positive-list compaction (block reservation)
__global__ __launch_bounds__(256) void k_emb(
    const float* __restrict__ off, const float* __restrict__ crd,
    const float* __restrict__ seed, const int* __restrict__ inst,
    float* __restrict__ seed_bg, float4* __restrict__ emb4,
    uint32_t* __restrict__ cursor, uint32_t* __restrict__ list)
{
  __shared__ uint32_t lcnt[K_], lbase[K_];
  __shared__ float red[4];
  const int b = blockIdx.y;
  const int tid = threadIdx.x;
  if (tid < K_) lcnt[tid] = 0;
  __syncthreads();

  const int n0 = blockIdx.x * 1024 + tid * 4;   // N_ % 4 == 0
  int kv[4];
  const bool valid = (n0 < N_);
  float sbg = 0.f;

  if (valid) {
    const int idx = b * N_ + n0;
    const float4* o4 = (const float4*)&off[(size_t)idx * 3];
    const float4* c4 = (const float4*)&crd[(size_t)idx * 3];
    float4 o0 = o4[0], o1 = o4[1], o2 = o4[2];
    float4 c0 = c4[0], c1 = c4[1], c2 = c4[2];
    int4 ki = *(const int4*)&inst[idx];
    kv[0] = ki.x; kv[1] = ki.y; kv[2] = ki.z; kv[3] = ki.w;

    emb4[idx + 0] = make_float4(fast_tanh(o0.x) + c0.x, fast_tanh(o0.y) + c0.y,
                                fast_tanh(o0.z) + c0.z, 0.f);
    emb4[idx + 1] = make_float4(fast_tanh(o0.w) + c0.w, fast_tanh(o1.x) + c1.x,
                                fast_tanh(o1.y) + c1.y, 0.f);
    emb4[idx + 2] = make_float4(fast_tanh(o1.z) + c1.z, fast_tanh(o1.w) + c1.w,
                                fast_tanh(o2.x) + c2.x, 0.f);
    emb4[idx + 3] = make_float4(fast_tanh(o2.y) + c2.y, fast_tanh(o2.z) + c2.z,
                                fast_tanh(o2.w) + c2.w, 0.f);

#pragma unroll
    for (int j = 0; j < 4; ++j) {
      if (kv[j] >= 0) {
        atomicAdd(&lcnt[kv[j]], 1u);
      } else {
        float s = fast_sigmoid(seed[idx + j]);
        sbg = fmaf(s, s, sbg);
      }
    }
  }
  __syncthreads();
  if (tid < K_) {
    uint32_t c = lcnt[tid];
    lbase[tid] = c ? atomicAdd(&cursor[b * K_ + tid], c) : 0u;
    lcnt[tid] = 0;
  }
  __syncthreads();
  if (valid) {
#pragma unroll
    for (int j = 0; j < 4; ++j) {
      if (kv[j] >= 0) {
        uint32_t r = atomicAdd(&lcnt[kv[j]], 1u);
        list[(uint32_t)((b * K_ + kv[j]) << SLOT_SHIFT) + lbase[kv[j]] + r] =
            (uint32_t)(n0 + j);
      }
    }
  }
  for (int d = 32; d > 0; d >>= 1) sbg += __shfl_down(sbg, d, 64);
  int wid = tid >> 6, lane = tid & 63;
  if (lane == 0) red[wid] = sbg;
  __syncthreads();
  if (tid == 0) atomicAdd(&seed_bg[b], red[0] + red[1] + red[2] + red[3]);
}

// per-seg stats as a clean reduction over the compacted list (no contention)
__global__ __launch_bounds__(256) void k_segstats(
    const float4* __restrict__ emb4, const float* __restrict__ sig,
    const uint32_t* __restrict__ list, const uint32_t* __restrict__ cursor,
    float* __restrict__ acc)
{
  __shared__ float red[4 * 8];
  const int seg = blockIdx.x >> 2;        // / SC
  const int c = blockIdx.x & (SC - 1);
  const int b = seg >> 5;
  const int G = (int)cursor[seg];
  if (G == 0) return;
  const int i0 = (int)((long)G * c / SC);
  const int i1 = (int)((long)G * (c + 1) / SC);
  const int base = b * N_;
  const uint32_t lo = (uint32_t)(seg << SLOT_SHIFT);
  const int tid = threadIdx.x;

  float sex_ = 0.f, sey_ = 0.f, sez_ = 0.f;
  float ssx = 0.f, ssy = 0.f, ssz = 0.f, ss2 = 0.f;
  for (int i = i0 + tid; i < i1; i += 256) {
    int idx = base + (int)list[lo + i];
    float4 e = emb4[idx];
    float sx = sig[(size_t)idx * 3 + 0];
    float sy = sig[(size_t)idx * 3 + 1];
    float sz = sig[(size_t)idx * 3 + 2];
    sex_ += e.x; sey_ += e.y; sez_ += e.z;
    ssx += sx; ssy += sy; ssz += sz;
    ss2 = fmaf(sx, sx, fmaf(sy, sy, fmaf(sz, sz, ss2)));
  }
  for (int d = 32; d > 0; d >>= 1) {
    sex_ += __shfl_down(sex_, d, 64); sey_ += __shfl_down(sey_, d, 64);
    sez_ += __shfl_down(sez_, d, 64); ssx  += __shfl_down(ssx,  d, 64);
    ssy  += __shfl_down(ssy,  d, 64); ssz  += __shfl_down(ssz,  d, 64);
    ss2  += __shfl_down(ss2,  d, 64);
  }
  int wid = tid >> 6, lane = tid & 63;
  if (lane == 0) {
    float* r = &red[wid * 8];
    r[0] = sex_; r[1] = sey_; r[2] = sez_;
    r[3] = ssx;  r[4] = ssy;  r[5] = ssz; r[6] = ss2;
  }
  __syncthreads();
  if (tid == 0) {
    float v[7];
    for (int f = 0; f < 7; ++f)
      v[f] = red[f] + red[8 + f] + red[16 + f] + red[24 + f];
    float* a = &acc[seg * 8];
    atomicAdd(&a[0], (float)(i1 - i0));
    atomicAdd(&a[1], v[0]); atomicAdd(&a[2], v[1]); atomicAdd(&a[3], v[2]);
    atomicAdd(&a[4], v[3]); atomicAdd(&a[5], v[4]); atomicAdd(&a[6], v[5]);
    atomicAdd(&a[7], v[6]);
  }
}

__global__ void k_params(const float* __restrict__ acc, float* __restrict__ p05)
{
  int seg = threadIdx.x;  // 0..127
  const float* a = &acc[seg * 8];
  float counts = a[0];
  float cnt = fmaxf(counts, 1.f);
  float inv = 1.f / cnt;
  float cx = a[1] * inv, cy = a[2] * inv, cz = a[3] * inv;
  float skx = a[4] * inv, sky = a[5] * inv, skz = a[6] * inv;
  float sex = expf(10.f * skx), sey = expf(10.f * sky), sez = expf(10.f * skz);
  float dev2 = a[7] - 2.f * (a[4] * skx + a[5] * sky + a[6] * skz)
             + counts * (skx * skx + sky * sky + skz * skz);
  float smooth = dev2 / (cnt * 3.f);
  float A = sex * cx * cx + sey * cy * cy + sez * cz * cz;
  float* o = &p05[seg * 16];
  o[0] = sex; o[1] = sey; o[2] = sez;
  o[3] = 2.f * sex * cx; o[4] = 2.f * sey * cy; o[5] = 2.f * sez * cz;
  o[6] = A; o[7] = counts; o[8] = (counts > 0.f) ? 1.f : 0.f; o[9] = smooth;
}

// grouped histogram: KG segs share each emb4 load; 4 x 16KB LDS hists (u32 only)
__global__ __launch_bounds__(512) void k_hist(
    const float4* __restrict__ emb4, const float* __restrict__ p05,
    uint32_t* __restrict__ hneg_g)
{
  __shared__ uint32_t h[KG * NB];   // 64 KB
  const int c = blockIdx.x & (HCH - 1);
  const int kg = blockIdx.x >> 4;
  const int b = blockIdx.y;
  const int seg0 = b * K_ + kg * KG;
  const int tid = threadIdx.x;

  float sexA[KG], seyA[KG], sezA[KG], txA[KG], tyA[KG], tzA[KG], AA[KG];
#pragma unroll
  for (int j = 0; j < KG; ++j) {
    const float* pp = &p05[(seg0 + j) * 16];
    sexA[j] = pp[0]; seyA[j] = pp[1]; sezA[j] = pp[2];
    txA[j] = pp[3]; tyA[j] = pp[4]; tzA[j] = pp[5]; AA[j] = pp[6];
  }
  for (int i = tid; i < KG * NB; i += 512) h[i] = 0;
  __syncthreads();

  const int base = b * N_;
  const int n0 = c * (N_ / HCH);
  const int n1 = n0 + (N_ / HCH);
  for (int n = n0 + tid; n < n1; n += 512) {
    float4 e = emb4[base + n];
#pragma unroll
    for (int j = 0; j < KG; ++j) {
      float qc = quad_qc(e, sexA[j], seyA[j], sezA[j], txA[j], tyA[j], tzA[j], AA[j]);
      atomicAdd(&h[j * NB + (__float_as_uint(qc) >> 19)], 1u);
    }
  }
  __syncthreads();
#pragma unroll
  for (int j = 0; j < KG; ++j) {
    uint32_t* gn = &hneg_g[(seg0 + j) * NB];
    for (int i = tid; i < NB; i += 512) {
      uint32_t v = h[j * NB + i];
      if (v) atomicAdd(&gn[i], v);
    }
  }
}

__device__ __forceinline__ void scan_excl(uint32_t* h, uint32_t* wsum, int tid)
{
  const int chunk = NB >> 10;  // 4
  const int base = tid * chunk;
  uint32_t vals[4];
  uint32_t s = 0;
  for (int i = 0; i < chunk; ++i) { vals[i] = h[base + i]; s += vals[i]; }
  uint32_t x = s;
  int lane = tid & 63;
  for (int d = 1; d < 64; d <<= 1) {
    uint32_t y = (uint32_t)__shfl_up((int)x, d, 64);
    if (lane >= d) x += y;
  }
  int wid = tid >> 6;
  if (lane == 63) wsum[wid] = x;
  __syncthreads();
  if (tid == 0) {
    uint32_t a = 0;
    for (int w = 0; w < 16; ++w) { uint32_t t = wsum[w]; wsum[w] = a; a += t; }
  }
  __syncthreads();
  uint32_t run = wsum[wid] + (x - s);
  for (int i = 0; i < chunk; ++i) { uint32_t t = vals[i]; h[base + i] = run; run += t; }
  __syncthreads();
}

// per-seg: remove positives from neg hist, build pos hist, scan both,
// emit COARSE fused neg table {u,v} (NB2), compute positive contributions
// (incl. subtracting the spurious coarse neg-style term pass2neg will add).
__global__ __launch_bounds__(1024) void k_scanpos(
    const float4* __restrict__ emb4, const float* __restrict__ seed,
    const float* __restrict__ p05, const uint32_t* __restrict__ list,
    uint32_t* __restrict__ hneg_g, float2* __restrict__ tabN,
    float* __restrict__ lov_out, float* __restrict__ seed_fg)
{
  __shared__ uint32_t hn[NB];
  __shared__ uint32_t hp[NB];
  __shared__ uint32_t wsum[16];
  __shared__ float red[32];
  const int seg = blockIdx.x;
  const int b = seg >> 5;
  const float* pp = &p05[seg * 16];
  const float Gf = pp[7];
  if (Gf <= 0.f) return;     // tabN stays zeroed -> pass2neg adds exact 0
  const float sex = pp[0], sey = pp[1], sez = pp[2];
  const float tx = pp[3], ty = pp[4], tz = pp[5], A = pp[6];
  const int tid = threadIdx.x;
  const int base = b * N_;
  const int G = (int)Gf;
  const uint32_t lo = (uint32_t)(seg << SLOT_SHIFT);
  const float Nnegf = (float)N_ - Gf;

  uint32_t* gn = &hneg_g[seg * NB];
  for (int i = tid; i < NB; i += 1024) { hn[i] = gn[i]; hp[i] = 0; }
  __syncthreads();

  // fixup: move this seg's positives out of hn, into hp (exp/log on 3% only)
  for (int i = tid; i < G; i += 1024) {
    int n = (int)list[lo + i];
    float qc = quad_qc(emb4[base + n], sex, sey, sez, tx, ty, tz, A);
    atomicAdd(&hn[__float_as_uint(qc) >> 19], 0xFFFFFFFFu);  // -1
    float p = __expf(-qc);
    float qs = -__logf(1.f - p);   // p==1 -> +inf -> bucket 4080, fine
    atomicAdd(&hp[__float_as_uint(qs) >> 19], 1u);
  }
  __syncthreads();
  scan_excl(hn, wsum, tid);
  scan_excl(hp, wsum, tid);

  // coarse fused neg table (sampled from fine cumulative scans at even idx)
  float2* tN = &tabN[(size_t)seg * NB2];
  for (int bkt = tid; bkt < NB2; bkt += 1024) {
    float R  = (float)hn[2 * bkt];
    float nn = (bkt < NB2 - 1) ? (float)hn[2 * bkt + 2] : Nnegf;
    float m  = nn - R;
    float pb = (float)hp[2 * bkt];
    float pn = (bkt < NB2 - 1) ? (float)hp[2 * bkt + 2] : Gf;
    float gr = Gf + R;
    float psi2 = 2.f / (gr * (gr + m));
    float u = psi2 * (Gf - pb);
    float v = psi2 * (pn - pb) * (1.f / 1048576.f);
    tN[bkt] = make_float2(u, v);
  }

  // positives' own contributions (fine-grained F interp)
  float lov = 0.f, sfg = 0.f;
  for (int i = tid; i < G; i += 1024) {
    int n = (int)list[lo + i];
    float qc = quad_qc(emb4[base + n], sex, sey, sez, tx, ty, tz, A);
    float p = __expf(-qc);
    float qs = -__logf(1.f - p);
    uint32_t qb = __float_as_uint(qs);
    uint32_t bk = qb >> 19;
    float frac = (float)(qb & 0x7FFFFu) * (1.f / 524288.f);
    float R  = (float)hn[bk];
    float nn = (bk < NB - 1) ? (float)hn[bk + 1] : Nnegf;
    float F = R + frac * (nn - R);
    lov += (2.f - 2.f * p) / (Gf + F);
    float s = fast_sigmoid(seed[base + n]);
    float d = s - p;
    sfg += d * d;
    // subtract the spurious COARSE neg-style term (bit-identical to table path)
    uint32_t cb = __float_as_uint(qc);
    uint32_t b2 = cb >> 20;
    float fr = (float)(cb & 0xFFFFFu);
    float R2  = (float)hn[2 * b2];
    float nn2 = (b2 < NB2 - 1) ? (float)hn[2 * b2 + 2] : Nnegf;
    float m2  = nn2 - R2;
    float pb2 = (float)hp[2 * b2];
    float pn2 = (b2 < NB2 - 1) ? (float)hp[2 * b2 + 2] : Gf;
    float gr2 = Gf + R2;
    float psi2 = 2.f / (gr2 * (gr2 + m2));
    float u2 = psi2 * (Gf - pb2);
    float v2 = psi2 * (pn2 - pb2) * (1.f / 1048576.f);
    lov -= p * fmaf(-v2, fr, u2);
  }

  for (int d = 32; d > 0; d >>= 1) {
    lov += __shfl_down(lov, d, 64);
    sfg += __shfl_down(sfg, d, 64);
  }
  int wid = tid >> 6, lane = tid & 63;
  if (lane == 0) { red[wid] = lov; red[16 + wid] = sfg; }
  __syncthreads();
  if (tid == 0) {
    float lt = 0.f, st = 0.f;
    for (int w = 0; w < 16; ++w) { lt += red[w]; st += red[16 + w]; }
    atomicAdd(&lov_out[seg], lt);
    atomicAdd(&seed_fg[b], st);
  }
}

// branch-free negative pass — EXACT R8 shape (best measured: 42.6 us).
// 1 seg/block, coarse 16KB global table (L1-resident hot region), 256 thr,
// 4-point stripe unroll for MLP. Do NOT regroup (R10/R11) or LDS-stage (R7).
__global__ __launch_bounds__(256) void k_pass2neg(
    const float4* __restrict__ emb4, const float* __restrict__ p05,
    const float2* __restrict__ tabN, float* __restrict__ lov_out)
{
  __shared__ float red[4];
  const int seg = blockIdx.x >> 4;          // / S2
  const int chunk = blockIdx.x & (S2 - 1);
  const int b = seg >> 5;
  const float* pp = &p05[seg * 16];
  const float Gf = pp[7];
  if (Gf <= 0.f) return;
  const float sex = pp[0], sey = pp[1], sez = pp[2];
  const float tx = pp[3], ty = pp[4], tz = pp[5], A = pp[6];
  const int tid = threadIdx.x;
  const int base = b * N_;
  const int n0 = chunk * (N_ / S2);         // 15625 per chunk
  const int nfull = n0 + 15360;             // 15 * 1024 full stripes
  const int n1 = n0 + (N_ / S2);
  const float2* tN = &tabN[(size_t)seg * NB2];

  float l0 = 0.f, l1 = 0.f, l2 = 0.f, l3 = 0.f;
  for (int s = n0 + tid; s < nfull; s += 1024) {
    float4 e0 = emb4[base + s];
    float4 e1 = emb4[base + s + 256];
    float4 e2 = emb4[base + s + 512];
    float4 e3 = emb4[base + s + 768];
    float q0 = quad_qc(e0, sex, sey, sez, tx, ty, tz, A);
    float q1 = quad_qc(e1, sex, sey, sez, tx, ty, tz, A);
    float q2 = quad_qc(e2, sex, sey, sez, tx, ty, tz, A);
    float q3 = quad_qc(e3, sex, sey, sez, tx, ty, tz, A);
    uint32_t c0 = __float_as_uint(q0), c1 = __float_as_uint(q1);
    uint32_t c2 = __float_as_uint(q2), c3 = __float_as_uint(q3);
    float2 t0 = tN[c0 >> 20];
    float2 t1 = tN[c1 >> 20];
    float2 t2 = tN[c2 >> 20];
    float2 t3 = tN[c3 >> 20];
    float p0 = __expf(-q0), p1 = __expf(-q1);
    float p2 = __expf(-q2), p3 = __expf(-q3);
    l0 = fmaf(p0, fmaf(-t0.y, (float)(c0 & 0xFFFFFu), t0.x), l0);
    l1 = fmaf(p1, fmaf(-t1.y, (float)(c1 & 0xFFFFFu), t1.x), l1);
    l2 = fmaf(p2, fmaf(-t2.y, (float)(c2 & 0xFFFFFu), t2.x), l2);
    l3 = fmaf(p3, fmaf(-t3.y, (float)(c3 & 0xFFFFFu), t3.x), l3);
  }
  for (int n = nfull + tid; n < n1; n += 256) {
    float qc = quad_qc(emb4[base + n], sex, sey, sez, tx, ty, tz, A);
    float p = __expf(-qc);
    uint32_t cb = __float_as_uint(qc);
    float2 t = tN[cb >> 20];
    l0 = fmaf(p, fmaf(-t.y, (float)(cb & 0xFFFFFu), t.x), l0);
  }

  float lov = (l0 + l1) + (l2 + l3);
  for (int d = 32; d > 0; d >>= 1) lov += __shfl_down(lov, d, 64);
  int wid = tid >> 6, lane = tid & 63;
  if (lane == 0) red[wid] = lov;
  __syncthreads();
  if (tid == 0) {
    float lt = red[0] + red[1] + red[2] + red[3];
    atomicAdd(&lov_out[seg], lt);
  }
}

__global__ void k_final(const float* __restrict__ p05, const float* __restrict__ lov,
                        const float* __restrict__ seed_bg, const float* __restrict__ seed_fg,
                        float* __restrict__ out)
{
  __shared__ float sv[B_], sl[B_], ss[B_];
  int tid = threadIdx.x;   // 128 threads, one per seg
  if (tid < B_) { sv[tid] = 0.f; sl[tid] = 0.f; ss[tid] = 0.f; }
  __syncthreads();
  int b = tid >> 5;
  float vf = p05[tid * 16 + 8];
  atomicAdd(&sv[b], vf);
  atomicAdd(&sl[b], lov[tid] * vf);
  atomicAdd(&ss[b], p05[tid * 16 + 9] * vf);
  __syncthreads();
  if (tid == 0) {
    float total = 0.f;
    for (int bb = 0; bb < B_; ++bb) {
      float obj = fmaxf(sv[bb], 1.f);
      float seed_l = (seed_bg[bb] + seed_fg[bb]) / (float)N_;
      total += sl[bb] / obj + 10.f * (ss[bb] / obj) + 10.f * seed_l;
    }
    out[0] = total / (float)B_;
  }
}

extern "C" void kernel_launch(void* const* d_in, const int* in_sizes, int n_in,
                              void* d_out, int out_size, void* d_ws, size_t ws_size,
                              hipStream_t stream) {
  const float* off  = (const float*)d_in[0];
  const float* crd  = (const float*)d_in[1];
  const float* sig  = (const float*)d_in[2];
  const float* seed = (const float*)d_in[3];
  const int*   inst = (const int*)d_in[4];

  float* ws      = (float*)d_ws;
  float* acc     = ws;                 // 1024 floats
  float* seed_bg = ws + 1024;          // 4
  float* seed_fg = ws + 1028;          // 4
  float* lov     = ws + 1032;          // 128
  uint32_t* cursor = (uint32_t*)(ws + 1160);  // 128
  float* p05     = ws + 2048;          // byte 8192
  char* pbase = (char*)d_ws;
  float4*   emb4   = (float4*)(pbase + 65536);                      // 16 MB
  uint32_t* hneg_g = (uint32_t*)(pbase + 65536 + 16000000);         // 2 MB
  float2*   tabN   = (float2*)(pbase + 65536 + 16000000 + 2097152); // 2 MB coarse
  uint32_t* list   = (uint32_t*)((char*)tabN + 2097152);            // 4 MB

  hipMemsetAsync(d_ws, 0, 8192, stream);
  hipMemsetAsync(hneg_g, 0, 4194304, stream);   // hneg_g + tabN (adjacent)

  dim3 ge((N_ + 1023) / 1024, B_);   // 245 x 4
  k_emb<<<ge, 256, 0, stream>>>(off, crd, seed, inst, seed_bg, emb4, cursor, list);
  k_segstats<<<B_ * K_ * SC, 256, 0, stream>>>(emb4, sig, list, cursor, acc);
  k_params<<<1, 128, 0, stream>>>(acc, p05);
  dim3 gh((K_ / KG) * HCH, B_);      // (8*16) x 4 = 512 blocks
  k_hist<<<gh, 512, 0, stream>>>(emb4, p05, hneg_g);
  k_scanpos<<<B_ * K_, 1024, 0, stream>>>(emb4, seed, p05, list, hneg_g, tabN, lov, seed_fg);
  k_pass2neg<<<B_ * K_ * S2, 256, 0, stream>>>(emb4, p05, tabN, lov);
  k_final<<<1, 128, 0, stream>>>(p05, lov, seed_bg, seed_fg, (float*)d_out);
}

// Round 13
// 209.910 us; speedup vs baseline: 1.3380x; 1.0231x over previous
//
#include <hip/hip_runtime.h>
#include <hip/hip_fp16.h>
#include <math.h>

#define B_ 4
#define N_ 250000
#define K_ 32
#define NB 4096    // fine buckets: (bits(qc) >> 19); nonneg floats -> <= 4080
#define NB2 2048   // coarse neg-table buckets: (bits >> 20)
#define KG 4       // segs grouped per hist block
#define HCH 16     // hist chunks over N  (N_/16 = 15625 exact)
#define S2 16      // pass2 chunks over N (R8 shape: best measured)
#define SC 4       // segstats chunks per seg
#define SLOT_SHIFT 13  // 8192 entries per seg in list

// ws layout: small accums @0 (8KB), p05 @8192, emb2 @65536 (8MB half4),
// hneg_g @65536+8MB (2MB), tabN next (2MB, zeroed with hneg), list next (4MB)

__device__ __forceinline__ uint32_t pack_h2(float a, float b) {
  __half2 h = __floats2half2_rn(a, b);
  return *(reinterpret_cast<uint32_t*>(&h));
}
__device__ __forceinline__ float2 unpack_h2(uint32_t u) {
  __half2 h = *(reinterpret_cast<__half2*>(&u));
  return __half22float2(h);
}

__device__ __forceinline__ float quad_qc(float ex, float ey, float ez,
                                         float sex, float sey, float sez,
                                         float tx, float ty, float tz, float A) {
  // explicit fmaf chain => bit-identical across kernels (bucket match requirement)
  float q = fmaf(ex, fmaf(sex, ex, -tx),
            fmaf(ey, fmaf(sey, ey, -ty),
            fmaf(ez, fmaf(sez, ez, -tz), A)));
  return fmaxf(q, 0.f);
}

__device__ __forceinline__ float fast_rcp(float x) { return __builtin_amdgcn_rcpf(x); }
__device__ __forceinline__ float fast_tanh(float x) {
  return 1.f - 2.f * fast_rcp(__expf(2.f * x) + 1.f);
}
__device__ __forceinline__ float fast_sigmoid(float x) {
  return fast_rcp(1.f + __expf(-x));
}

// emb compute (packed half4 out) + positive-list compaction (block reservation)
__global__ __launch_bounds__(256) void k_emb(
    const float* __restrict__ off, const float* __restrict__ crd,
    const float* __restrict__ seed, const int* __restrict__ inst,
    float* __restrict__ seed_bg, uint2* __restrict__ emb2,
    uint32_t* __restrict__ cursor, uint32_t* __restrict__ list)
{
  __shared__ uint32_t lcnt[K_], lbase[K_];
  __shared__ float red[4];
  const int b = blockIdx.y;
  const int tid = threadIdx.x;
  if (tid < K_) lcnt[tid] = 0;
  __syncthreads();

  const int n0 = blockIdx.x * 1024 + tid * 4;   // N_ % 4 == 0
  int kv[4];
  const bool valid = (n0 < N_);
  float sbg = 0.f;

  if (valid) {
    const int idx = b * N_ + n0;
    const float4* o4 = (const float4*)&off[(size_t)idx * 3];
    const float4* c4 = (const float4*)&crd[(size_t)idx * 3];
    float4 o0 = o4[0], o1 = o4[1], o2 = o4[2];
    float4 c0 = c4[0], c1 = c4[1], c2 = c4[2];
    int4 ki = *(const int4*)&inst[idx];
    kv[0] = ki.x; kv[1] = ki.y; kv[2] = ki.z; kv[3] = ki.w;

    float ex0 = fast_tanh(o0.x) + c0.x, ey0 = fast_tanh(o0.y) + c0.y, ez0 = fast_tanh(o0.z) + c0.z;
    float ex1 = fast_tanh(o0.w) + c0.w, ey1 = fast_tanh(o1.x) + c1.x, ez1 = fast_tanh(o1.y) + c1.y;
    float ex2 = fast_tanh(o1.z) + c1.z, ey2 = fast_tanh(o1.w) + c1.w, ez2 = fast_tanh(o2.x) + c2.x;
    float ex3 = fast_tanh(o2.y) + c2.y, ey3 = fast_tanh(o2.z) + c2.z, ez3 = fast_tanh(o2.w) + c2.w;
    uint4 w0, w1;
    w0.x = pack_h2(ex0, ey0); w0.y = pack_h2(ez0, 0.f);
    w0.z = pack_h2(ex1, ey1); w0.w = pack_h2(ez1, 0.f);
    w1.x = pack_h2(ex2, ey2); w1.y = pack_h2(ez2, 0.f);
    w1.z = pack_h2(ex3, ey3); w1.w = pack_h2(ez3, 0.f);
    ((uint4*)&emb2[idx])[0] = w0;   // idx % 4 == 0 -> 32B aligned
    ((uint4*)&emb2[idx])[1] = w1;

#pragma unroll
    for (int j = 0; j < 4; ++j) {
      if (kv[j] >= 0) {
        atomicAdd(&lcnt[kv[j]], 1u);
      } else {
        float s = fast_sigmoid(seed[idx + j]);
        sbg = fmaf(s, s, sbg);
      }
    }
  }
  __syncthreads();
  if (tid < K_) {
    uint32_t c = lcnt[tid];
    lbase[tid] = c ? atomicAdd(&cursor[b * K_ + tid], c) : 0u;
    lcnt[tid] = 0;
  }
  __syncthreads();
  if (valid) {
#pragma unroll
    for (int j = 0; j < 4; ++j) {
      if (kv[j] >= 0) {
        uint32_t r = atomicAdd(&lcnt[kv[j]], 1u);
        list[(uint32_t)((b * K_ + kv[j]) << SLOT_SHIFT) + lbase[kv[j]] + r] =
            (uint32_t)(n0 + j);
      }
    }
  }
  for (int d = 32; d > 0; d >>= 1) sbg += __shfl_down(sbg, d, 64);
  int wid = tid >> 6, lane = tid & 63;
  if (lane == 0) red[wid] = sbg;
  __syncthreads();
  if (tid == 0) atomicAdd(&seed_bg[b], red[0] + red[1] + red[2] + red[3]);
}

// per-seg stats as a clean reduction over the compacted list (no contention)
__global__ __launch_bounds__(256) void k_segstats(
    const uint2* __restrict__ emb2, const float* __restrict__ sig,
    const uint32_t* __restrict__ list, const uint32_t* __restrict__ cursor,
    float* __restrict__ acc)
{
  __shared__ float red[4 * 8];
  const int seg = blockIdx.x >> 2;        // / SC
  const int c = blockIdx.x & (SC - 1);
  const int b = seg >> 5;
  const int G = (int)cursor[seg];
  if (G == 0) return;
  const int i0 = (int)((long)G * c / SC);
  const int i1 = (int)((long)G * (c + 1) / SC);
  const int base = b * N_;
  const uint32_t lo = (uint32_t)(seg << SLOT_SHIFT);
  const int tid = threadIdx.x;

  float sex_ = 0.f, sey_ = 0.f, sez_ = 0.f;
  float ssx = 0.f, ssy = 0.f, ssz = 0.f, ss2 = 0.f;
  for (int i = i0 + tid; i < i1; i += 256) {
    int idx = base + (int)list[lo + i];
    uint2 e = emb2[idx];
    float2 xy = unpack_h2(e.x);
    float2 zw = unpack_h2(e.y);
    float sx = sig[(size_t)idx * 3 + 0];
    float sy = sig[(size_t)idx * 3 + 1];
    float sz = sig[(size_t)idx * 3 + 2];
    sex_ += xy.x; sey_ += xy.y; sez_ += zw.x;
    ssx += sx; ssy += sy; ssz += sz;
    ss2 = fmaf(sx, sx, fmaf(sy, sy, fmaf(sz, sz, ss2)));
  }
  for (int d = 32; d > 0; d >>= 1) {
    sex_ += __shfl_down(sex_, d, 64); sey_ += __shfl_down(sey_, d, 64);
    sez_ += __shfl_down(sez_, d, 64); ssx  += __shfl_down(ssx,  d, 64);
    ssy  += __shfl_down(ssy,  d, 64); ssz  += __shfl_down(ssz,  d, 64);
    ss2  += __shfl_down(ss2,  d, 64);
  }
  int wid = tid >> 6, lane = tid & 63;
  if (lane == 0) {
    float* r = &red[wid * 8];
    r[0] = sex_; r[1] = sey_; r[2] = sez_;
    r[3] = ssx;  r[4] = ssy;  r[5] = ssz; r[6] = ss2;
  }
  __syncthreads();
  if (tid == 0) {
    float v[7];
    for (int f = 0; f < 7; ++f)
      v[f] = red[f] + red[8 + f] + red[16 + f] + red[24 + f];
    float* a = &acc[seg * 8];
    atomicAdd(&a[0], (float)(i1 - i0));
    atomicAdd(&a[1], v[0]); atomicAdd(&a[2], v[1]); atomicAdd(&a[3], v[2]);
    atomicAdd(&a[4], v[3]); atomicAdd(&a[5], v[4]); atomicAdd(&a[6], v[5]);
    atomicAdd(&a[7], v[6]);
  }
}

__global__ void k_params(const float* __restrict__ acc, float* __restrict__ p05)
{
  int seg = threadIdx.x;  // 0..127
  const float* a = &acc[seg * 8];
  float counts = a[0];
  float cnt = fmaxf(counts, 1.f);
  float inv = 1.f / cnt;
  float cx = a[1] * inv, cy = a[2] * inv, cz = a[3] * inv;
  float skx = a[4] * inv, sky = a[5] * inv, skz = a[6] * inv;
  float sex = expf(10.f * skx), sey = expf(10.f * sky), sez = expf(10.f * skz);
  float dev2 = a[7] - 2.f * (a[4] * skx + a[5] * sky + a[6] * skz)
             + counts * (skx * skx + sky * sky + skz * skz);
  float smooth = dev2 / (cnt * 3.f);
  float A = sex * cx * cx + sey * cy * cy + sez * cz * cz;
  float* o = &p05[seg * 16];
  o[0] = sex; o[1] = sey; o[2] = sez;
  o[3] = 2.f * sex * cx; o[4] = 2.f * sey * cy; o[5] = 2.f * sez * cz;
  o[6] = A; o[7] = counts; o[8] = (counts > 0.f) ? 1.f : 0.f; o[9] = smooth;
}

// grouped histogram: KG segs share each emb load; 4 x 16KB LDS hists (u32 only)
__global__ __launch_bounds__(512) void k_hist(
    const uint2* __restrict__ emb2, const float* __restrict__ p05,
    uint32_t* __restrict__ hneg_g)
{
  __shared__ uint32_t h[KG * NB];   // 64 KB
  const int c = blockIdx.x & (HCH - 1);
  const int kg = blockIdx.x >> 4;
  const int b = blockIdx.y;
  const int seg0 = b * K_ + kg * KG;
  const int tid = threadIdx.x;

  float sexA[KG], seyA[KG], sezA[KG], txA[KG], tyA[KG], tzA[KG], AA[KG];
#pragma unroll
  for (int j = 0; j < KG; ++j) {
    const float* pp = &p05[(seg0 + j) * 16];
    sexA[j] = pp[0]; seyA[j] = pp[1]; sezA[j] = pp[2];
    txA[j] = pp[3]; tyA[j] = pp[4]; tzA[j] = pp[5]; AA[j] = pp[6];
  }
  for (int i = tid; i < KG * NB; i += 512) h[i] = 0;
  __syncthreads();

  const int base = b * N_;
  const int n0 = c * (N_ / HCH);
  const int n1 = n0 + (N_ / HCH);
  for (int n = n0 + tid; n < n1; n += 512) {
    uint2 e = emb2[base + n];
    float2 xy = unpack_h2(e.x);
    float2 zw = unpack_h2(e.y);
#pragma unroll
    for (int j = 0; j < KG; ++j) {
      float qc = quad_qc(xy.x, xy.y, zw.x,
                         sexA[j], seyA[j], sezA[j], txA[j], tyA[j], tzA[j], AA[j]);
      atomicAdd(&h[j * NB + (__float_as_uint(qc) >> 19)], 1u);
    }
  }
  __syncthreads();
#pragma unroll
  for (int j = 0; j < KG; ++j) {
    uint32_t* gn = &hneg_g[(seg0 + j) * NB];
    for (int i = tid; i < NB; i += 512) {
      uint32_t v = h[j * NB + i];
      if (v) atomicAdd(&gn[i], v);
    }
  }
}

__device__ __forceinline__ void scan_excl(uint32_t* h, uint32_t* wsum, int tid)
{
  const int chunk = NB >> 10;  // 4
  const int base = tid * chunk;
  uint32_t vals[4];
  uint32_t s = 0;
  for (int i = 0; i < chunk; ++i) { vals[i] = h[base + i]; s += vals[i]; }
  uint32_t x = s;
  int lane = tid & 63;
  for (int d = 1; d < 64; d <<= 1) {
    uint32_t y = (uint32_t)__shfl_up((int)x, d, 64);
    if (lane >= d) x += y;
  }
  int wid = tid >> 6;
  if (lane == 63) wsum[wid] = x;
  __syncthreads();
  if (tid == 0) {
    uint32_t a = 0;
    for (int w = 0; w < 16; ++w) { uint32_t t = wsum[w]; wsum[w] = a; a += t; }
  }
  __syncthreads();
  uint32_t run = wsum[wid] + (x - s);
  for (int i = 0; i < chunk; ++i) { uint32_t t = vals[i]; h[base + i] = run; run += t; }
  __syncthreads();
}

// per-seg: remove positives from neg hist, build pos hist, scan both,
// emit COARSE fused neg table {u,v} (NB2), compute positive contributions
// (incl. subtracting the spurious coarse neg-style term pass2neg will add).
__global__ __launch_bounds__(1024) void k_scanpos(
    const uint2* __restrict__ emb2, const float* __restrict__ seed,
    const float* __restrict__ p05, const uint32_t* __restrict__ list,
    uint32_t* __restrict__ hneg_g, float2* __restrict__ tabN,
    float* __restrict__ lov_out, float* __restrict__ seed_fg)
{
  __shared__ uint32_t hn[NB];
  __shared__ uint32_t hp[NB];
  __shared__ uint32_t wsum[16];
  __shared__ float red[32];
  const int seg = blockIdx.x;
  const int b = seg >> 5;
  const float* pp = &p05[seg * 16];
  const float Gf = pp[7];
  if (Gf <= 0.f) return;     // tabN stays zeroed -> pass2neg adds exact 0
  const float sex = pp[0], sey = pp[1], sez = pp[2];
  const float tx = pp[3], ty = pp[4], tz = pp[5], A = pp[6];
  const int tid = threadIdx.x;
  const int base = b * N_;
  const int G = (int)Gf;
  const uint32_t lo = (uint32_t)(seg << SLOT_SHIFT);
  const float Nnegf = (float)N_ - Gf;

  uint32_t* gn = &hneg_g[seg * NB];
  for (int i = tid; i < NB; i += 1024) { hn[i] = gn[i]; hp[i] = 0; }
  __syncthreads();

  // fixup: move this seg's positives out of hn, into hp (exp/log on 3% only)
  for (int i = tid; i < G; i += 1024) {
    int n = (int)list[lo + i];
    uint2 e = emb2[base + n];
    float2 xy = unpack_h2(e.x);
    float2 zw = unpack_h2(e.y);
    float qc = quad_qc(xy.x, xy.y, zw.x, sex, sey, sez, tx, ty, tz, A);
    atomicAdd(&hn[__float_as_uint(qc) >> 19], 0xFFFFFFFFu);  // -1
    float p = __expf(-qc);
    float qs = -__logf(1.f - p);   // p==1 -> +inf -> bucket 4080, fine
    atomicAdd(&hp[__float_as_uint(qs) >> 19], 1u);
  }
  __syncthreads();
  scan_excl(hn, wsum, tid);
  scan_excl(hp, wsum, tid);

  // coarse fused neg table (sampled from fine cumulative scans at even idx)
  float2* tN = &tabN[(size_t)seg * NB2];
  for (int bkt = tid; bkt < NB2; bkt += 1024) {
    float R  = (float)hn[2 * bkt];
    float nn = (bkt < NB2 - 1) ? (float)hn[2 * bkt + 2] : Nnegf;
    float m  = nn - R;
    float pb = (float)hp[2 * bkt];
    float pn = (bkt < NB2 - 1) ? (float)hp[2 * bkt + 2] : Gf;
    float gr = Gf + R;
    float psi2 = 2.f / (gr * (gr + m));
    float u = psi2 * (Gf - pb);
    float v = psi2 * (pn - pb) * (1.f / 1048576.f);
    tN[bkt] = make_float2(u, v);
  }

  // positives' own contributions (fine-grained F interp)
  float lov = 0.f, sfg = 0.f;
  for (int i = tid; i < G; i += 1024) {
    int n = (int)list[lo + i];
    uint2 e = emb2[base + n];
    float2 xy = unpack_h2(e.x);
    float2 zw = unpack_h2(e.y);
    float qc = quad_qc(xy.x, xy.y, zw.x, sex, sey, sez, tx, ty, tz, A);
    float p = __expf(-qc);
    float qs = -__logf(1.f - p);
    uint32_t qb = __float_as_uint(qs);
    uint32_t bk = qb >> 19;
    float frac = (float)(qb & 0x7FFFFu) * (1.f / 524288.f);
    float R  = (float)hn[bk];
    float nn = (bk < NB - 1) ? (float)hn[bk + 1] : Nnegf;
    float F = R + frac * (nn - R);
    lov += (2.f - 2.f * p) / (Gf + F);
    float s = fast_sigmoid(seed[base + n]);
    float d = s - p;
    sfg += d * d;
    // subtract the spurious COARSE neg-style term (bit-identical to table path)
    uint32_t cb = __float_as_uint(qc);
    uint32_t b2 = cb >> 20;
    float fr = (float)(cb & 0xFFFFFu);
    float R2  = (float)hn[2 * b2];
    float nn2 = (b2 < NB2 - 1) ? (float)hn[2 * b2 + 2] : Nnegf;
    float m2  = nn2 - R2;
    float pb2 = (float)hp[2 * b2];
    float pn2 = (b2 < NB2 - 1) ? (float)hp[2 * b2 + 2] : Gf;
    float gr2 = Gf + R2;
    float psi2 = 2.f / (gr2 * (gr2 + m2));
    float u2 = psi2 * (Gf - pb2);
    float v2 = psi2 * (pn2 - pb2) * (1.f / 1048576.f);
    lov -= p * fmaf(-v2, fr, u2);
  }

  for (int d = 32; d > 0; d >>= 1) {
    lov += __shfl_down(lov, d, 64);
    sfg += __shfl_down(sfg, d, 64);
  }
  int wid = tid >> 6, lane = tid & 63;
  if (lane == 0) { red[wid] = lov; red[16 + wid] = sfg; }
  __syncthreads();
  if (tid == 0) {
    float lt = 0.f, st = 0.f;
    for (int w = 0; w < 16; ++w) { lt += red[w]; st += red[16 + w]; }
    atomicAdd(&lov_out[seg], lt);
    atomicAdd(&seed_fg[b], st);
  }
}

// branch-free negative pass — R8 shape (best measured), now on 8B packed emb.
// 1 seg/block, coarse 16KB global table (L1-resident hot region), 256 thr,
// 4-point stripe unroll for MLP. Do NOT regroup (R10/R11) or LDS-stage (R7).
__global__ __launch_bounds__(256) void k_pass2neg(
    const uint2* __restrict__ emb2, const float* __restrict__ p05,
    const float2* __restrict__ tabN, float* __restrict__ lov_out)
{
  __shared__ float red[4];
  const int seg = blockIdx.x >> 4;          // / S2
  const int chunk = blockIdx.x & (S2 - 1);
  const int b = seg >> 5;
  const float* pp = &p05[seg * 16];
  const float Gf = pp[7];
  if (Gf <= 0.f) return;
  const float sex = pp[0], sey = pp[1], sez = pp[2];
  const float tx = pp[3], ty = pp[4], tz = pp[5], A = pp[6];
  const int tid = threadIdx.x;
  const int base = b * N_;
  const int n0 = chunk * (N_ / S2);         // 15625 per chunk
  const int nfull = n0 + 15360;             // 15 * 1024 full stripes
  const int n1 = n0 + (N_ / S2);
  const float2* tN = &tabN[(size_t)seg * NB2];

  float l0 = 0.f, l1 = 0.f, l2 = 0.f, l3 = 0.f;
  for (int s = n0 + tid; s < nfull; s += 1024) {
    uint2 e0 = emb2[base + s];
    uint2 e1 = emb2[base + s + 256];
    uint2 e2 = emb2[base + s + 512];
    uint2 e3 = emb2[base + s + 768];
    float2 a0 = unpack_h2(e0.x), b0 = unpack_h2(e0.y);
    float2 a1 = unpack_h2(e1.x), b1 = unpack_h2(e1.y);
    float2 a2 = unpack_h2(e2.x), b2 = unpack_h2(e2.y);
    float2 a3 = unpack_h2(e3.x), b3 = unpack_h2(e3.y);
    float q0 = quad_qc(a0.x, a0.y, b0.x, sex, sey, sez, tx, ty, tz, A);
    float q1 = quad_qc(a1.x, a1.y, b1.x, sex, sey, sez, tx, ty, tz, A);
    float q2 = quad_qc(a2.x, a2.y, b2.x, sex, sey, sez, tx, ty, tz, A);
    float q3 = quad_qc(a3.x, a3.y, b3.x, sex, sey, sez, tx, ty, tz, A);
    uint32_t c0 = __float_as_uint(q0), c1 = __float_as_uint(q1);
    uint32_t c2 = __float_as_uint(q2), c3 = __float_as_uint(q3);
    float2 t0 = tN[c0 >> 20];
    float2 t1 = tN[c1 >> 20];
    float2 t2 = tN[c2 >> 20];
    float2 t3 = tN[c3 >> 20];
    float p0 = __expf(-q0), p1 = __expf(-q1);
    float p2 = __expf(-q2), p3 = __expf(-q3);
    l0 = fmaf(p0, fmaf(-t0.y, (float)(c0 & 0xFFFFFu), t0.x), l0);
    l1 = fmaf(p1, fmaf(-t1.y, (float)(c1 & 0xFFFFFu), t1.x), l1);
    l2 = fmaf(p2, fmaf(-t2.y, (float)(c2 & 0xFFFFFu), t2.x), l2);
    l3 = fmaf(p3, fmaf(-t3.y, (float)(c3 & 0xFFFFFu), t3.x), l3);
  }
  for (int n = nfull + tid; n < n1; n += 256) {
    uint2 e = emb2[base + n];
    float2 xy = unpack_h2(e.x);
    float2 zw = unpack_h2(e.y);
    float qc = quad_qc(xy.x, xy.y, zw.x, sex, sey, sez, tx, ty, tz, A);
    float p = __expf(-qc);
    uint32_t cb = __float_as_uint(qc);
    float2 t = tN[cb >> 20];
    l0 = fmaf(p, fmaf(-t.y, (float)(cb & 0xFFFFFu), t.x), l0);
  }

  float lov = (l0 + l1) + (l2 + l3);
  for (int d = 32; d > 0; d >>= 1) lov += __shfl_down(lov, d, 64);
  int wid = tid >> 6, lane = tid & 63;
  if (lane == 0) red[wid] = lov;
  __syncthreads();
  if (tid == 0) {
    float lt = red[0] + red[1] + red[2] + red[3];
    atomicAdd(&lov_out[seg], lt);
  }
}

__global__ void k_final(const float* __restrict__ p05, const float* __restrict__ lov,
                        const float* __restrict__ seed_bg, const float* __restrict__ seed_fg,
                        float* __restrict__ out)
{
  __shared__ float sv[B_], sl[B_], ss[B_];
  int tid = threadIdx.x;   // 128 threads, one per seg
  if (tid < B_) { sv[tid] = 0.f; sl[tid] = 0.f; ss[tid] = 0.f; }
  __syncthreads();
  int b = tid >> 5;
  float vf = p05[tid * 16 + 8];
  atomicAdd(&sv[b], vf);
  atomicAdd(&sl[b], lov[tid] * vf);
  atomicAdd(&ss[b], p05[tid * 16 + 9] * vf);
  __syncthreads();
  if (tid == 0) {
    float total = 0.f;
    for (int bb = 0; bb < B_; ++bb) {
      float obj = fmaxf(sv[bb], 1.f);
      float seed_l = (seed_bg[bb] + seed_fg[bb]) / (float)N_;
      total += sl[bb] / obj + 10.f * (ss[bb] / obj) + 10.f * seed_l;
    }
    out[0] = total / (float)B_;
  }
}

extern "C" void kernel_launch(void* const* d_in, const int* in_sizes, int n_in,
                              void* d_out, int out_size, void* d_ws, size_t ws_size,
                              hipStream_t stream) {
  const float* off  = (const float*)d_in[0];
  const float* crd  = (const float*)d_in[1];
  const float* sig  = (const float*)d_in[2];
  const float* seed = (const float*)d_in[3];
  const int*   inst = (const int*)d_in[4];

  float* ws      = (float*)d_ws;
  float* acc     = ws;                 // 1024 floats
  float* seed_bg = ws + 1024;          // 4
  float* seed_fg = ws + 1028;          // 4
  float* lov     = ws + 1032;          // 128
  uint32_t* cursor = (uint32_t*)(ws + 1160);  // 128
  float* p05     = ws + 2048;          // byte 8192
  char* pbase = (char*)d_ws;
  uint2*    emb2   = (uint2*)(pbase + 65536);                       // 8 MB half4
  uint32_t* hneg_g = (uint32_t*)(pbase + 65536 + 8388608);          // 2 MB
  float2*   tabN   = (float2*)(pbase + 65536 + 8388608 + 2097152);  // 2 MB coarse
  uint32_t* list   = (uint32_t*)((char*)tabN + 2097152);            // 4 MB

  hipMemsetAsync(d_ws, 0, 8192, stream);
  hipMemsetAsync(hneg_g, 0, 4194304, stream);   // hneg_g + tabN (adjacent)

  dim3 ge((N_ + 1023) / 1024, B_);   // 245 x 4
  k_emb<<<ge, 256, 0, stream>>>(off, crd, seed, inst, seed_bg, emb2, cursor, list);
  k_segstats<<<B_ * K_ * SC, 256, 0, stream>>>(emb2, sig, list, cursor, acc);
  k_params<<<1, 128, 0, stream>>>(acc, p05);
  dim3 gh((K_ / KG) * HCH, B_);      // (8*16) x 4 = 512 blocks
  k_hist<<<gh, 512, 0, stream>>>(emb2, p05, hneg_g);
  k_scanpos<<<B_ * K_, 1024, 0, stream>>>(emb2, seed, p05, list, hneg_g, tabN, lov, seed_fg);
  k_pass2neg<<<B_ * K_ * S2, 256, 0, stream>>>(emb2, p05, tabN, lov);
  k_final<<<1, 128, 0, stream>>>(p05, lov, seed_bg, seed_fg, (float*)d_out);
}

// Round 14
// 208.729 us; speedup vs baseline: 1.3456x; 1.0057x over previous
//
#include <hip/hip_runtime.h>
#include <hip/hip_fp16.h>
#include <math.h>

#define B_ 4
#define N_ 250000
#define K_ 32
#define NB 4096    // fine buckets: (bits(qc) >> 19); nonneg floats -> <= 4080
#define NB2 2048   // coarse neg-table buckets: (bits >> 20)
#define KG 2       // segs grouped per hist block (R13 post-mortem: KG=4 -> 64KB
                   // LDS -> 2 blocks/CU = 50% occupancy cap; KG=2 -> 32KB -> 4
                   // blocks/CU = 100%. Stream doubles but emb2 is 2MB/batch = L2)
#define HCH 16     // hist chunks over N  (N_/16 = 15625 exact)
#define S2 16      // pass2 chunks over N (R8 shape: best measured)
#define SC 4       // segstats chunks per seg
#define SLOT_SHIFT 13  // 8192 entries per seg in list

// ws layout: small accums @0 (8KB), p05 @8192, emb2 @65536 (8MB half4),
// hneg_g @65536+8MB (2MB), tabN next (2MB, zeroed with hneg), list next (4MB)

__device__ __forceinline__ uint32_t pack_h2(float a, float b) {
  __half2 h = __floats2half2_rn(a, b);
  return *(reinterpret_cast<uint32_t*>(&h));
}
__device__ __forceinline__ float2 unpack_h2(uint32_t u) {
  __half2 h = *(reinterpret_cast<__half2*>(&u));
  return __half22float2(h);
}

__device__ __forceinline__ float quad_qc(float ex, float ey, float ez,
                                         float sex, float sey, float sez,
                                         float tx, float ty, float tz, float A) {
  // explicit fmaf chain => bit-identical across kernels (bucket match requirement)
  float q = fmaf(ex, fmaf(sex, ex, -tx),
            fmaf(ey, fmaf(sey, ey, -ty),
            fmaf(ez, fmaf(sez, ez, -tz), A)));
  return fmaxf(q, 0.f);
}

__device__ __forceinline__ float fast_rcp(float x) { return __builtin_amdgcn_rcpf(x); }
__device__ __forceinline__ float fast_tanh(float x) {
  return 1.f - 2.f * fast_rcp(__expf(2.f * x) + 1.f);
}
__device__ __forceinline__ float fast_sigmoid(float x) {
  return fast_rcp(1.f + __expf(-x));
}

// emb compute (packed half4 out) + positive-list compaction (block reservation)
__global__ __launch_bounds__(256) void k_emb(
    const float* __restrict__ off, const float* __restrict__ crd,
    const float* __restrict__ seed, const int* __restrict__ inst,
    float* __restrict__ seed_bg, uint2* __restrict__ emb2,
    uint32_t* __restrict__ cursor, uint32_t* __restrict__ list)
{
  __shared__ uint32_t lcnt[K_], lbase[K_];
  __shared__ float red[4];
  const int b = blockIdx.y;
  const int tid = threadIdx.x;
  if (tid < K_) lcnt[tid] = 0;
  __syncthreads();

  const int n0 = blockIdx.x * 1024 + tid * 4;   // N_ % 4 == 0
  int kv[4];
  const bool valid = (n0 < N_);
  float sbg = 0.f;

  if (valid) {
    const int idx = b * N_ + n0;
    const float4* o4 = (const float4*)&off[(size_t)idx * 3];
    const float4* c4 = (const float4*)&crd[(size_t)idx * 3];
    float4 o0 = o4[0], o1 = o4[1], o2 = o4[2];
    float4 c0 = c4[0], c1 = c4[1], c2 = c4[2];
    int4 ki = *(const int4*)&inst[idx];
    kv[0] = ki.x; kv[1] = ki.y; kv[2] = ki.z; kv[3] = ki.w;

    float ex0 = fast_tanh(o0.x) + c0.x, ey0 = fast_tanh(o0.y) + c0.y, ez0 = fast_tanh(o0.z) + c0.z;
    float ex1 = fast_tanh(o0.w) + c0.w, ey1 = fast_tanh(o1.x) + c1.x, ez1 = fast_tanh(o1.y) + c1.y;
    float ex2 = fast_tanh(o1.z) + c1.z, ey2 = fast_tanh(o1.w) + c1.w, ez2 = fast_tanh(o2.x) + c2.x;
    float ex3 = fast_tanh(o2.y) + c2.y, ey3 = fast_tanh(o2.z) + c2.z, ez3 = fast_tanh(o2.w) + c2.w;
    uint4 w0, w1;
    w0.x = pack_h2(ex0, ey0); w0.y = pack_h2(ez0, 0.f);
    w0.z = pack_h2(ex1, ey1); w0.w = pack_h2(ez1, 0.f);
    w1.x = pack_h2(ex2, ey2); w1.y = pack_h2(ez2, 0.f);
    w1.z = pack_h2(ex3, ey3); w1.w = pack_h2(ez3, 0.f);
    ((uint4*)&emb2[idx])[0] = w0;   // idx % 4 == 0 -> 32B aligned
    ((uint4*)&emb2[idx])[1] = w1;

#pragma unroll
    for (int j = 0; j < 4; ++j) {
      if (kv[j] >= 0) {
        atomicAdd(&lcnt[kv[j]], 1u);
      } else {
        float s = fast_sigmoid(seed[idx + j]);
        sbg = fmaf(s, s, sbg);
      }
    }
  }
  __syncthreads();
  if (tid < K_) {
    uint32_t c = lcnt[tid];
    lbase[tid] = c ? atomicAdd(&cursor[b * K_ + tid], c) : 0u;
    lcnt[tid] = 0;
  }
  __syncthreads();
  if (valid) {
#pragma unroll
    for (int j = 0; j < 4; ++j) {
      if (kv[j] >= 0) {
        uint32_t r = atomicAdd(&lcnt[kv[j]], 1u);
        list[(uint32_t)((b * K_ + kv[j]) << SLOT_SHIFT) + lbase[kv[j]] + r] =
            (uint32_t)(n0 + j);
      }
    }
  }
  for (int d = 32; d > 0; d >>= 1) sbg += __shfl_down(sbg, d, 64);
  int wid = tid >> 6, lane = tid & 63;
  if (lane == 0) red[wid] = sbg;
  __syncthreads();
  if (tid == 0) atomicAdd(&seed_bg[b], red[0] + red[1] + red[2] + red[3]);
}

// per-seg stats as a clean reduction over the compacted list (no contention)
__global__ __launch_bounds__(256) void k_segstats(
    const uint2* __restrict__ emb2, const float* __restrict__ sig,
    const uint32_t* __restrict__ list, const uint32_t* __restrict__ cursor,
    float* __restrict__ acc)
{
  __shared__ float red[4 * 8];
  const int seg = blockIdx.x >> 2;        // / SC
  const int c = blockIdx.x & (SC - 1);
  const int b = seg >> 5;
  const int G = (int)cursor[seg];
  if (G == 0) return;
  const int i0 = (int)((long)G * c / SC);
  const int i1 = (int)((long)G * (c + 1) / SC);
  const int base = b * N_;
  const uint32_t lo = (uint32_t)(seg << SLOT_SHIFT);
  const int tid = threadIdx.x;

  float sex_ = 0.f, sey_ = 0.f, sez_ = 0.f;
  float ssx = 0.f, ssy = 0.f, ssz = 0.f, ss2 = 0.f;
  for (int i = i0 + tid; i < i1; i += 256) {
    int idx = base + (int)list[lo + i];
    uint2 e = emb2[idx];
    float2 xy = unpack_h2(e.x);
    float2 zw = unpack_h2(e.y);
    float sx = sig[(size_t)idx * 3 + 0];
    float sy = sig[(size_t)idx * 3 + 1];
    float sz = sig[(size_t)idx * 3 + 2];
    sex_ += xy.x; sey_ += xy.y; sez_ += zw.x;
    ssx += sx; ssy += sy; ssz += sz;
    ss2 = fmaf(sx, sx, fmaf(sy, sy, fmaf(sz, sz, ss2)));
  }
  for (int d = 32; d > 0; d >>= 1) {
    sex_ += __shfl_down(sex_, d, 64); sey_ += __shfl_down(sey_, d, 64);
    sez_ += __shfl_down(sez_, d, 64); ssx  += __shfl_down(ssx,  d, 64);
    ssy  += __shfl_down(ssy,  d, 64); ssz  += __shfl_down(ssz,  d, 64);
    ss2  += __shfl_down(ss2,  d, 64);
  }
  int wid = tid >> 6, lane = tid & 63;
  if (lane == 0) {
    float* r = &red[wid * 8];
    r[0] = sex_; r[1] = sey_; r[2] = sez_;
    r[3] = ssx;  r[4] = ssy;  r[5] = ssz; r[6] = ss2;
  }
  __syncthreads();
  if (tid == 0) {
    float v[7];
    for (int f = 0; f < 7; ++f)
      v[f] = red[f] + red[8 + f] + red[16 + f] + red[24 + f];
    float* a = &acc[seg * 8];
    atomicAdd(&a[0], (float)(i1 - i0));
    atomicAdd(&a[1], v[0]); atomicAdd(&a[2], v[1]); atomicAdd(&a[3], v[2]);
    atomicAdd(&a[4], v[3]); atomicAdd(&a[5], v[4]); atomicAdd(&a[6], v[5]);
    atomicAdd(&a[7], v[6]);
  }
}

__global__ void k_params(const float* __restrict__ acc, float* __restrict__ p05)
{
  int seg = threadIdx.x;  // 0..127
  const float* a = &acc[seg * 8];
  float counts = a[0];
  float cnt = fmaxf(counts, 1.f);
  float inv = 1.f / cnt;
  float cx = a[1] * inv, cy = a[2] * inv, cz = a[3] * inv;
  float skx = a[4] * inv, sky = a[5] * inv, skz = a[6] * inv;
  float sex = expf(10.f * skx), sey = expf(10.f * sky), sez = expf(10.f * skz);
  float dev2 = a[7] - 2.f * (a[4] * skx + a[5] * sky + a[6] * skz)
             + counts * (skx * skx + sky * sky + skz * skz);
  float smooth = dev2 / (cnt * 3.f);
  float A = sex * cx * cx + sey * cy * cy + sez * cz * cz;
  float* o = &p05[seg * 16];
  o[0] = sex; o[1] = sey; o[2] = sez;
  o[3] = 2.f * sex * cx; o[4] = 2.f * sey * cy; o[5] = 2.f * sez * cz;
  o[6] = A; o[7] = counts; o[8] = (counts > 0.f) ? 1.f : 0.f; o[9] = smooth;
}

// grouped histogram: KG=2 segs share each emb load; 2 x 16KB LDS hists
// -> 32KB/block -> 4 blocks/CU -> 32 waves/CU (100% occupancy cap)
__global__ __launch_bounds__(512) void k_hist(
    const uint2* __restrict__ emb2, const float* __restrict__ p05,
    uint32_t* __restrict__ hneg_g)
{
  __shared__ uint32_t h[KG * NB];   // 32 KB
  const int c = blockIdx.x & (HCH - 1);
  const int kg = blockIdx.x >> 4;
  const int b = blockIdx.y;
  const int seg0 = b * K_ + kg * KG;
  const int tid = threadIdx.x;

  float sexA[KG], seyA[KG], sezA[KG], txA[KG], tyA[KG], tzA[KG], AA[KG];
#pragma unroll
  for (int j = 0; j < KG; ++j) {
    const float* pp = &p05[(seg0 + j) * 16];
    sexA[j] = pp[0]; seyA[j] = pp[1]; sezA[j] = pp[2];
    txA[j] = pp[3]; tyA[j] = pp[4]; tzA[j] = pp[5]; AA[j] = pp[6];
  }
  for (int i = tid; i < KG * NB; i += 512) h[i] = 0;
  __syncthreads();

  const int base = b * N_;
  const int n0 = c * (N_ / HCH);
  const int n1 = n0 + (N_ / HCH);
  for (int n = n0 + tid; n < n1; n += 512) {
    uint2 e = emb2[base + n];
    float2 xy = unpack_h2(e.x);
    float2 zw = unpack_h2(e.y);
#pragma unroll
    for (int j = 0; j < KG; ++j) {
      float qc = quad_qc(xy.x, xy.y, zw.x,
                         sexA[j], seyA[j], sezA[j], txA[j], tyA[j], tzA[j], AA[j]);
      atomicAdd(&h[j * NB + (__float_as_uint(qc) >> 19)], 1u);
    }
  }
  __syncthreads();
#pragma unroll
  for (int j = 0; j < KG; ++j) {
    uint32_t* gn = &hneg_g[(seg0 + j) * NB];
    for (int i = tid; i < NB; i += 512) {
      uint32_t v = h[j * NB + i];
      if (v) atomicAdd(&gn[i], v);
    }
  }
}

__device__ __forceinline__ void scan_excl(uint32_t* h, uint32_t* wsum, int tid)
{
  const int chunk = NB >> 10;  // 4
  const int base = tid * chunk;
  uint32_t vals[4];
  uint32_t s = 0;
  for (int i = 0; i < chunk; ++i) { vals[i] = h[base + i]; s += vals[i]; }
  uint32_t x = s;
  int lane = tid & 63;
  for (int d = 1; d < 64; d <<= 1) {
    uint32_t y = (uint32_t)__shfl_up((int)x, d, 64);
    if (lane >= d) x += y;
  }
  int wid = tid >> 6;
  if (lane == 63) wsum[wid] = x;
  __syncthreads();
  if (tid == 0) {
    uint32_t a = 0;
    for (int w = 0; w < 16; ++w) { uint32_t t = wsum[w]; wsum[w] = a; a += t; }
  }
  __syncthreads();
  uint32_t run = wsum[wid] + (x - s);
  for (int i = 0; i < chunk; ++i) { uint32_t t = vals[i]; h[base + i] = run; run += t; }
  __syncthreads();
}

// per-seg: remove positives from neg hist, build pos hist, scan both,
// emit COARSE fused neg table {u,v} (NB2), compute positive contributions
// (incl. subtracting the spurious coarse neg-style term pass2neg will add).
__global__ __launch_bounds__(1024) void k_scanpos(
    const uint2* __restrict__ emb2, const float* __restrict__ seed,
    const float* __restrict__ p05, const uint32_t* __restrict__ list,
    uint32_t* __restrict__ hneg_g, float2* __restrict__ tabN,
    float* __restrict__ lov_out, float* __restrict__ seed_fg)
{
  __shared__ uint32_t hn[NB];
  __shared__ uint32_t hp[NB];
  __shared__ uint32_t wsum[16];
  __shared__ float red[32];
  const int seg = blockIdx.x;
  const int b = seg >> 5;
  const float* pp = &p05[seg * 16];
  const float Gf = pp[7];
  if (Gf <= 0.f) return;     // tabN stays zeroed -> pass2neg adds exact 0
  const float sex = pp[0], sey = pp[1], sez = pp[2];
  const float tx = pp[3], ty = pp[4], tz = pp[5], A = pp[6];
  const int tid = threadIdx.x;
  const int base = b * N_;
  const int G = (int)Gf;
  const uint32_t lo = (uint32_t)(seg << SLOT_SHIFT);
  const float Nnegf = (float)N_ - Gf;

  uint32_t* gn = &hneg_g[seg * NB];
  for (int i = tid; i < NB; i += 1024) { hn[i] = gn[i]; hp[i] = 0; }
  __syncthreads();

  // fixup: move this seg's positives out of hn, into hp (exp/log on 3% only)
  for (int i = tid; i < G; i += 1024) {
    int n = (int)list[lo + i];
    uint2 e = emb2[base + n];
    float2 xy = unpack_h2(e.x);
    float2 zw = unpack_h2(e.y);
    float qc = quad_qc(xy.x, xy.y, zw.x, sex, sey, sez, tx, ty, tz, A);
    atomicAdd(&hn[__float_as_uint(qc) >> 19], 0xFFFFFFFFu);  // -1
    float p = __expf(-qc);
    float qs = -__logf(1.f - p);   // p==1 -> +inf -> bucket 4080, fine
    atomicAdd(&hp[__float_as_uint(qs) >> 19], 1u);
  }
  __syncthreads();
  scan_excl(hn, wsum, tid);
  scan_excl(hp, wsum, tid);

  // coarse fused neg table (sampled from fine cumulative scans at even idx)
  float2* tN = &tabN[(size_t)seg * NB2];
  for (int bkt = tid; bkt < NB2; bkt += 1024) {
    float R  = (float)hn[2 * bkt];
    float nn = (bkt < NB2 - 1) ? (float)hn[2 * bkt + 2] : Nnegf;
    float m  = nn - R;
    float pb = (float)hp[2 * bkt];
    float pn = (bkt < NB2 - 1) ? (float)hp[2 * bkt + 2] : Gf;
    float gr = Gf + R;
    float psi2 = 2.f / (gr * (gr + m));
    float u = psi2 * (Gf - pb);
    float v = psi2 * (pn - pb) * (1.f / 1048576.f);
    tN[bkt] = make_float2(u, v);
  }

  // positives' own contributions (fine-grained F interp)
  float lov = 0.f, sfg = 0.f;
  for (int i = tid; i < G; i += 1024) {
    int n = (int)list[lo + i];
    uint2 e = emb2[base + n];
    float2 xy = unpack_h2(e.x);
    float2 zw = unpack_h2(e.y);
    float qc = quad_qc(xy.x, xy.y, zw.x, sex, sey, sez, tx, ty, tz, A);
    float p = __expf(-qc);
    float qs = -__logf(1.f - p);
    uint32_t qb = __float_as_uint(qs);
    uint32_t bk = qb >> 19;
    float frac = (float)(qb & 0x7FFFFu) * (1.f / 524288.f);
    float R  = (float)hn[bk];
    float nn = (bk < NB - 1) ? (float)hn[bk + 1] : Nnegf;
    float F = R + frac * (nn - R);
    lov += (2.f - 2.f * p) / (Gf + F);
    float s = fast_sigmoid(seed[base + n]);
    float d = s - p;
    sfg += d * d;
    // subtract the spurious COARSE neg-style term (bit-identical to table path)
    uint32_t cb = __float_as_uint(qc);
    uint32_t b2 = cb >> 20;
    float fr = (float)(cb & 0xFFFFFu);
    float R2  = (float)hn[2 * b2];
    float nn2 = (b2 < NB2 - 1) ? (float)hn[2 * b2 + 2] : Nnegf;
    float m2  = nn2 - R2;
    float pb2 = (float)hp[2 * b2];
    float pn2 = (b2 < NB2 - 1) ? (float)hp[2 * b2 + 2] : Gf;
    float gr2 = Gf + R2;
    float psi2 = 2.f / (gr2 * (gr2 + m2));
    float u2 = psi2 * (Gf - pb2);
    float v2 = psi2 * (pn2 - pb2) * (1.f / 1048576.f);
    lov -= p * fmaf(-v2, fr, u2);
  }

  for (int d = 32; d > 0; d >>= 1) {
    lov += __shfl_down(lov, d, 64);
    sfg += __shfl_down(sfg, d, 64);
  }
  int wid = tid >> 6, lane = tid & 63;
  if (lane == 0) { red[wid] = lov; red[16 + wid] = sfg; }
  __syncthreads();
  if (tid == 0) {
    float lt = 0.f, st = 0.f;
    for (int w = 0; w < 16; ++w) { lt += red[w]; st += red[16 + w]; }
    atomicAdd(&lov_out[seg], lt);
    atomicAdd(&seed_fg[b], st);
  }
}

// branch-free negative pass — R8 shape (best measured), 8B packed emb.
// 1 seg/block, coarse 16KB global table (L1-resident hot region), 256 thr,
// 4-point stripe unroll for MLP. Do NOT regroup (R10/R11) or LDS-stage (R7).
__global__ __launch_bounds__(256) void k_pass2neg(
    const uint2* __restrict__ emb2, const float* __restrict__ p05,
    const float2* __restrict__ tabN, float* __restrict__ lov_out)
{
  __shared__ float red[4];
  const int seg = blockIdx.x >> 4;          // / S2
  const int chunk = blockIdx.x & (S2 - 1);
  const int b = seg >> 5;
  const float* pp = &p05[seg * 16];
  const float Gf = pp[7];
  if (Gf <= 0.f) return;
  const float sex = pp[0], sey = pp[1], sez = pp[2];
  const float tx = pp[3], ty = pp[4], tz = pp[5], A = pp[6];
  const int tid = threadIdx.x;
  const int base = b * N_;
  const int n0 = chunk * (N_ / S2);         // 15625 per chunk
  const int nfull = n0 + 15360;             // 15 * 1024 full stripes
  const int n1 = n0 + (N_ / S2);
  const float2* tN = &tabN[(size_t)seg * NB2];

  float l0 = 0.f, l1 = 0.f, l2 = 0.f, l3 = 0.f;
  for (int s = n0 + tid; s < nfull; s += 1024) {
    uint2 e0 = emb2[base + s];
    uint2 e1 = emb2[base + s + 256];
    uint2 e2 = emb2[base + s + 512];
    uint2 e3 = emb2[base + s + 768];
    float2 a0 = unpack_h2(e0.x), b0 = unpack_h2(e0.y);
    float2 a1 = unpack_h2(e1.x), b1 = unpack_h2(e1.y);
    float2 a2 = unpack_h2(e2.x), b2 = unpack_h2(e2.y);
    float2 a3 = unpack_h2(e3.x), b3 = unpack_h2(e3.y);
    float q0 = quad_qc(a0.x, a0.y, b0.x, sex, sey, sez, tx, ty, tz, A);
    float q1 = quad_qc(a1.x, a1.y, b1.x, sex, sey, sez, tx, ty, tz, A);
    float q2 = quad_qc(a2.x, a2.y, b2.x, sex, sey, sez, tx, ty, tz, A);
    float q3 = quad_qc(a3.x, a3.y, b3.x, sex, sey, sez, tx, ty, tz, A);
    uint32_t c0 = __float_as_uint(q0), c1 = __float_as_uint(q1);
    uint32_t c2 = __float_as_uint(q2), c3 = __float_as_uint(q3);
    float2 t0 = tN[c0 >> 20];
    float2 t1 = tN[c1 >> 20];
    float2 t2 = tN[c2 >> 20];
    float2 t3 = tN[c3 >> 20];
    float p0 = __expf(-q0), p1 = __expf(-q1);
    float p2 = __expf(-q2), p3 = __expf(-q3);
    l0 = fmaf(p0, fmaf(-t0.y, (float)(c0 & 0xFFFFFu), t0.x), l0);
    l1 = fmaf(p1, fmaf(-t1.y, (float)(c1 & 0xFFFFFu), t1.x), l1);
    l2 = fmaf(p2, fmaf(-t2.y, (float)(c2 & 0xFFFFFu), t2.x), l2);
    l3 = fmaf(p3, fmaf(-t3.y, (float)(c3 & 0xFFFFFu), t3.x), l3);
  }
  for (int n = nfull + tid; n < n1; n += 256) {
    uint2 e = emb2[base + n];
    float2 xy = unpack_h2(e.x);
    float2 zw = unpack_h2(e.y);
    float qc = quad_qc(xy.x, xy.y, zw.x, sex, sey, sez, tx, ty, tz, A);
    float p = __expf(-qc);
    uint32_t cb = __float_as_uint(qc);
    float2 t = tN[cb >> 20];
    l0 = fmaf(p, fmaf(-t.y, (float)(cb & 0xFFFFFu), t.x), l0);
  }

  float lov = (l0 + l1) + (l2 + l3);
  for (int d = 32; d > 0; d >>= 1) lov += __shfl_down(lov, d, 64);
  int wid = tid >> 6, lane = tid & 63;
  if (lane == 0) red[wid] = lov;
  __syncthreads();
  if (tid == 0) {
    float lt = red[0] + red[1] + red[2] + red[3];
    atomicAdd(&lov_out[seg], lt);
  }
}

__global__ void k_final(const float* __restrict__ p05, const float* __restrict__ lov,
                        const float* __restrict__ seed_bg, const float* __restrict__ seed_fg,
                        float* __restrict__ out)
{
  __shared__ float sv[B_], sl[B_], ss[B_];
  int tid = threadIdx.x;   // 128 threads, one per seg
  if (tid < B_) { sv[tid] = 0.f; sl[tid] = 0.f; ss[tid] = 0.f; }
  __syncthreads();
  int b = tid >> 5;
  float vf = p05[tid * 16 + 8];
  atomicAdd(&sv[b], vf);
  atomicAdd(&sl[b], lov[tid] * vf);
  atomicAdd(&ss[b], p05[tid * 16 + 9] * vf);
  __syncthreads();
  if (tid == 0) {
    float total = 0.f;
    for (int bb = 0; bb < B_; ++bb) {
      float obj = fmaxf(sv[bb], 1.f);
      float seed_l = (seed_bg[bb] + seed_fg[bb]) / (float)N_;
      total += sl[bb] / obj + 10.f * (ss[bb] / obj) + 10.f * seed_l;
    }
    out[0] = total / (float)B_;
  }
}

extern "C" void kernel_launch(void* const* d_in, const int* in_sizes, int n_in,
                              void* d_out, int out_size, void* d_ws, size_t ws_size,
                              hipStream_t stream) {
  const float* off  = (const float*)d_in[0];
  const float* crd  = (const float*)d_in[1];
  const float* sig  = (const float*)d_in[2];
  const float* seed = (const float*)d_in[3];
  const int*   inst = (const int*)d_in[4];

  float* ws      = (float*)d_ws;
  float* acc     = ws;                 // 1024 floats
  float* seed_bg = ws + 1024;          // 4
  float* seed_fg = ws + 1028;          // 4
  float* lov     = ws + 1032;          // 128
  uint32_t* cursor = (uint32_t*)(ws + 1160);  // 128
  float* p05     = ws + 2048;          // byte 8192
  char* pbase = (char*)d_ws;
  uint2*    emb2   = (uint2*)(pbase + 65536);                       // 8 MB half4
  uint32_t* hneg_g = (uint32_t*)(pbase + 65536 + 8388608);          // 2 MB
  float2*   tabN   = (float2*)(pbase + 65536 + 8388608 + 2097152);  // 2 MB coarse
  uint32_t* list   = (uint32_t*)((char*)tabN + 2097152);            // 4 MB

  hipMemsetAsync(d_ws, 0, 8192, stream);
  hipMemsetAsync(hneg_g, 0, 4194304, stream);   // hneg_g + tabN (adjacent)

  dim3 ge((N_ + 1023) / 1024, B_);   // 245 x 4
  k_emb<<<ge, 256, 0, stream>>>(off, crd, seed, inst, seed_bg, emb2, cursor, list);
  k_segstats<<<B_ * K_ * SC, 256, 0, stream>>>(emb2, sig, list, cursor, acc);
  k_params<<<1, 128, 0, stream>>>(acc, p05);
  dim3 gh((K_ / KG) * HCH, B_);      // (16*16) x 4 = 1024 blocks
  k_hist<<<gh, 512, 0, stream>>>(emb2, p05, hneg_g);
  k_scanpos<<<B_ * K_, 1024, 0, stream>>>(emb2, seed, p05, list, hneg_g, tabN, lov, seed_fg);
  k_pass2neg<<<B_ * K_ * S2, 256, 0, stream>>>(emb2, p05, tabN, lov);
  k_final<<<1, 128, 0, stream>>>(p05, lov, seed_bg, seed_fg, (float*)d_out);
}